// Round 10
// baseline (364.276 us; speedup 1.0000x reference)
//
#include <hip/hip_runtime.h>

#define N_NODES 100000
#define N_PAD   100352        // 392*256
#define N_EDGES 3200000
#define IN_DIM  128
#define HID     64
#define N_GRAPHS 256
#define NB      392           // buckets of 256 dest nodes each
#define NBLK    256           // hist/scatter blocks
#define EPB     (N_EDGES / NBLK)   // 12500
#define G1ROWS  64                 // rows per gemm1 block (MFMA tile)
#define G1BLK   (N_PAD / G1ROWS)   // 1568 gemm1 blocks
#define DBINS   1024               // degree histogram bins

typedef unsigned short ushort_t;
typedef unsigned int   uint_t;
typedef __attribute__((ext_vector_type(4))) float f32x4;
typedef __attribute__((ext_vector_type(8))) short bf16x8;

// bf16 helpers: storage-only compression of the gathered operand
__device__ __forceinline__ ushort_t f2bf(float v) {          // round-to-nearest-even
    uint_t b = __float_as_uint(v);
    b += 0x7fffu + ((b >> 16) & 1u);
    return (ushort_t)(b >> 16);
}
__device__ __forceinline__ void bf2f2(uint_t u, float& lo, float& hi) {
    lo = __uint_as_float(u << 16);
    hi = __uint_as_float(u & 0xffff0000u);
}
// 16B load -> 8 floats
__device__ __forceinline__ void ld_bf16x8(const ushort_t* p, float4& a, float4& b) {
    uint4 u = *(const uint4*)p;
    bf2f2(u.x, a.x, a.y); bf2f2(u.y, a.z, a.w);
    bf2f2(u.z, b.x, b.y); bf2f2(u.w, b.z, b.w);
}
// unpack a loaded uint4 (8 bf16) and FMA into the accumulators with weight w
__device__ __forceinline__ void fma8(float4& a0, float4& a1, const uint4& u, float w) {
    float lo, hi;
    bf2f2(u.x, lo, hi); a0.x += lo * w; a0.y += hi * w;
    bf2f2(u.y, lo, hi); a0.z += lo * w; a0.w += hi * w;
    bf2f2(u.z, lo, hi); a1.x += lo * w; a1.y += hi * w;
    bf2f2(u.w, lo, hi); a1.z += lo * w; a1.w += hi * w;
}
// clamped edge-record load: pad slots re-read the last valid record with weight 0
__device__ __forceinline__ int2 ldrec(const int2* __restrict__ csr, int last, int idx) {
    int2 r = csr[idx <= last ? idx : last];
    if (idx > last) r.y = 0;
    return r;
}

// ---------- phase 0: W1 -> transposed split-bf16 planes Wt_hi/Wt_lo [64][128] ----------
// Also zeroes the degree histogram for this iteration.
__global__ __launch_bounds__(256) void wtprep_kernel(const float* __restrict__ W1,
                                                     ushort_t* __restrict__ Wt,
                                                     int* __restrict__ hist) {
    int i = blockIdx.x * 256 + threadIdx.x;      // 0..8191, i = k*64 + c
    if (i < DBINS) hist[i] = 0;
    int k = i >> 6, c = i & 63;
    float w = W1[i];
    ushort_t hi = f2bf(w);
    float rem = w - __uint_as_float((uint_t)hi << 16);
    ushort_t lo = f2bf(rem);
    Wt[c * 128 + k]        = hi;                 // Wt_hi [64][128]
    Wt[8192 + c * 128 + k] = lo;                 // Wt_lo [64][128]
}

// ---------- phase 1 (fused): bucket histogram (blocks 0..NBLK-1) + MFMA gemm1 ----------
__global__ __launch_bounds__(256) void bhist_gemm1_kernel(
        const int* __restrict__ col, int* __restrict__ H,
        const float* __restrict__ x, const ushort_t* __restrict__ Wt,
        ushort_t* __restrict__ xl) {
    __shared__ char smem[49152];       // hist: 3.1KB | gemm: sA 16K + sBh 16K + sBl 16K
    int tid = threadIdx.x;
    if (blockIdx.x < NBLK) {
        int (*h)[NB] = (int (*)[NB])smem;
        for (int i = tid; i < NB; i += 256) { h[0][i] = 0; h[1][i] = 0; }
        __syncthreads();
        const int4* col4 = (const int4*)col;
        int base4 = blockIdx.x * (EPB / 4);
        int sel = tid & 1;
        for (int j = tid; j < EPB / 4; j += 256) {
            int4 c = col4[base4 + j];
            atomicAdd(&h[sel][c.x >> 8], 1);
            atomicAdd(&h[sel][c.y >> 8], 1);
            atomicAdd(&h[sel][c.z >> 8], 1);
            atomicAdd(&h[sel][c.w >> 8], 1);
        }
        __syncthreads();
        for (int i = tid; i < NB; i += 256) H[i * NBLK + blockIdx.x] = h[0][i] + h[1][i];
    } else {
        int bid = blockIdx.x - NBLK;
        ushort_t* sA  = (ushort_t*)smem;          // [64][128] bf16, swizzled
        ushort_t* sBh = sA + 8192;                // [64][128] bf16, swizzled
        ushort_t* sBl = sBh + 8192;
        int r0 = bid * G1ROWS;
        // stage A: thread t -> row t>>2, 32-col chunk (t&3)*32; fp32 -> bf16
        {
            int row = tid >> 2;
            int ck  = (tid & 3) * 32;
            int gr  = r0 + row; if (gr >= N_NODES) gr = 0;     // pad rows: dummy data
            const float4* xs = (const float4*)(x + (size_t)gr * IN_DIM + ck);
            #pragma unroll
            for (int j = 0; j < 4; ++j) {
                float4 a = xs[2 * j], b = xs[2 * j + 1];
                uint4 u;
                u.x = (uint_t)f2bf(a.x) | ((uint_t)f2bf(a.y) << 16);
                u.y = (uint_t)f2bf(a.z) | ((uint_t)f2bf(a.w) << 16);
                u.z = (uint_t)f2bf(b.x) | ((uint_t)f2bf(b.y) << 16);
                u.w = (uint_t)f2bf(b.z) | ((uint_t)f2bf(b.w) << 16);
                int byte = (row * 256 + ck * 2 + j * 16) ^ ((row & 7) << 4);
                *(uint4*)(smem + byte) = u;
            }
            // stage B planes: linear 16B units -> swizzled LDS
            const uint4* wh = (const uint4*)Wt;
            const uint4* wl = (const uint4*)(Wt + 8192);
            #pragma unroll
            for (int j = 0; j < 4; ++j) {
                int u16  = tid * 4 + j;                 // 0..1023
                int colb = u16 >> 4, kc = u16 & 15;
                int byte = (colb * 256 + kc * 16) ^ ((colb & 7) << 4);
                *(uint4*)((char*)sBh + byte) = wh[u16];
                *(uint4*)((char*)sBl + byte) = wl[u16];
            }
        }
        __syncthreads();
        int wv   = tid >> 6, lane = tid & 63;
        int m0   = wv * 16;
        int fr   = lane & 15;
        int fkb  = (lane >> 4) * 16;       // byte offset of k-slice (8 bf16)
        int arow = m0 + fr;
        int aswz = (arow & 7) << 4;
        int bswz = (fr & 7) << 4;
        f32x4 acc0 = {0.f, 0.f, 0.f, 0.f}, acc1 = acc0, acc2 = acc0, acc3 = acc0;
        #pragma unroll
        for (int ks = 0; ks < 4; ++ks) {
            int kb = ks * 64 + fkb;
            bf16x8 af = *(const bf16x8*)((const char*)sA + ((arow * 256 + kb) ^ aswz));
#define BSTEP(ACC, n0) { \
            int bb = (((n0 + fr) * 256 + kb) ^ bswz); \
            bf16x8 bh = *(const bf16x8*)((const char*)sBh + bb); \
            bf16x8 bl = *(const bf16x8*)((const char*)sBl + bb); \
            ACC = __builtin_amdgcn_mfma_f32_16x16x32_bf16(af, bh, ACC, 0, 0, 0); \
            ACC = __builtin_amdgcn_mfma_f32_16x16x32_bf16(af, bl, ACC, 0, 0, 0); }
            BSTEP(acc0, 0) BSTEP(acc1, 16) BSTEP(acc2, 32) BSTEP(acc3, 48)
#undef BSTEP
        }
        // transpose D through LDS (stride 72 bf16), then 2 coalesced uint4 stores
        __syncthreads();                           // all MFMA LDS reads done
        ushort_t* sO = (ushort_t*)smem;            // [64][72] bf16 = 9216 B
        int orow = m0 + (lane >> 4) * 4;
#define TSTORE(reg) { ushort_t* sp = sO + (orow + reg) * 72; \
        sp[fr]      = f2bf(acc0[reg]); sp[fr + 16] = f2bf(acc1[reg]); \
        sp[fr + 32] = f2bf(acc2[reg]); sp[fr + 48] = f2bf(acc3[reg]); }
        TSTORE(0) TSTORE(1) TSTORE(2) TSTORE(3)
#undef TSTORE
        __syncthreads();
        int r  = tid >> 2;                         // 0..63
        int cb = (tid & 3) * 16;                   // col 0/16/32/48
        int gr2 = r0 + r;
        if (gr2 < N_NODES) {
            const uint4* sp = (const uint4*)(sO + r * 72 + cb);
            uint4* dp = (uint4*)(xl + (size_t)gr2 * HID + cb);
            dp[0] = sp[0];
            dp[1] = sp[1];
        }
    }
}

// ---------- phase 2: exclusive scan of H (NB*NBLK, bucket-major) ----------
__global__ __launch_bounds__(256) void scan1_kernel(int* H, int* __restrict__ bsum) {
    __shared__ int s[256];
    int i = blockIdx.x * 256 + threadIdx.x;   // blockIdx.x == bucket (NBLK==256)
    int v = H[i];
    s[threadIdx.x] = v;
    __syncthreads();
    #pragma unroll
    for (int off = 1; off < 256; off <<= 1) {
        int t = (threadIdx.x >= off) ? s[threadIdx.x - off] : 0;
        __syncthreads();
        s[threadIdx.x] += t;
        __syncthreads();
    }
    H[i] = s[threadIdx.x] - v;                           // exclusive within bucket
    if (threadIdx.x == 255) bsum[blockIdx.x] = s[255];   // bucket total
}

// ---------- phase 3: LDS-staged scatter — bucket-sort in LDS, coalesced burst out ----------
// rec = (row | local<<17, ew); local = col & 255 (8 bits), row < 2^17
__global__ __launch_bounds__(256) void bscatter_kernel(const int* __restrict__ row,
                                                       const int* __restrict__ col,
                                                       const float* __restrict__ ew,
                                                       const int* __restrict__ H,
                                                       const int* __restrict__ bsum,
                                                       int* __restrict__ boff,
                                                       int2* __restrict__ recs) {
    __shared__ int2 lrec[EPB];        // 100 KB: the block's records, bucket-sorted
    __shared__ int  lofs[NB];
    __shared__ int  hcnt[NB];
    __shared__ int  gofs[NB];
    __shared__ int  cur[NB];
    __shared__ int  s[256];
    __shared__ int  carry;
    int tid = threadIdx.x, blk = blockIdx.x;
    if (tid == 0) carry = 0;
    __syncthreads();
    for (int c = 0; c < 2; ++c) {                 // 2*256 >= NB
        int i = c * 256 + tid;
        int v = (i < NB) ? bsum[i] : 0;
        s[tid] = v;
        __syncthreads();
        #pragma unroll
        for (int off = 1; off < 256; off <<= 1) {
            int t = (tid >= off) ? s[tid - off] : 0;
            __syncthreads();
            s[tid] += t;
            __syncthreads();
        }
        if (i < NB) {
            int tb = s[tid] - v + carry;          // bucket start in recs
            int ex = H[i * NBLK + blk];
            gofs[i] = tb + ex;
            hcnt[i] = ((blk < NBLK - 1) ? H[i * NBLK + blk + 1] : v) - ex;
            if (blk == 0) boff[i] = tb;
        }
        __syncthreads();
        if (tid == 0) carry += s[255];
        __syncthreads();
    }
    if (tid == 0) carry = 0;
    __syncthreads();
    for (int c = 0; c < 2; ++c) {
        int i = c * 256 + tid;
        int v = (i < NB) ? hcnt[i] : 0;
        s[tid] = v;
        __syncthreads();
        #pragma unroll
        for (int off = 1; off < 256; off <<= 1) {
            int t = (tid >= off) ? s[tid - off] : 0;
            __syncthreads();
            s[tid] += t;
            __syncthreads();
        }
        if (i < NB) { int l = s[tid] - v + carry; lofs[i] = l; cur[i] = l; }
        __syncthreads();
        if (tid == 0) carry += s[255];
        __syncthreads();
    }
    const int4*   row4 = (const int4*)row;
    const int4*   col4 = (const int4*)col;
    const float4* ew4  = (const float4*)ew;
    int base4 = blk * (EPB / 4);
    for (int j = tid; j < EPB / 4; j += 256) {
        int4   r4 = row4[base4 + j];
        int4   c4 = col4[base4 + j];
        float4 w4 = ew4[base4 + j];
        int p0 = atomicAdd(&cur[c4.x >> 8], 1);
        lrec[p0] = make_int2(r4.x | ((c4.x & 255) << 17), __float_as_int(w4.x));
        int p1 = atomicAdd(&cur[c4.y >> 8], 1);
        lrec[p1] = make_int2(r4.y | ((c4.y & 255) << 17), __float_as_int(w4.y));
        int p2 = atomicAdd(&cur[c4.z >> 8], 1);
        lrec[p2] = make_int2(r4.z | ((c4.z & 255) << 17), __float_as_int(w4.z));
        int p3 = atomicAdd(&cur[c4.w >> 8], 1);
        lrec[p3] = make_int2(r4.w | ((c4.w & 255) << 17), __float_as_int(w4.w));
    }
    __syncthreads();
    int wv = tid >> 6, lane = tid & 63;
    for (int i = wv; i < NB; i += 4) {
        int cnt = hcnt[i], lo = lofs[i], go = gofs[i];
        for (int k = lane; k < cnt; k += 64)
            recs[go + k] = lrec[lo + k];
    }
}

// ---------- phase 3.5 (fused): recs pass -> deg+cnt -> dis/rowptr -> csr permutation
// scatter -> yl scale tail. Also feeds the global degree histogram (LDS-aggregated).
__global__ __launch_bounds__(1024) void degcsr_kernel(const int2* __restrict__ recs,
                                                      const int* __restrict__ boff,
                                                      float* __restrict__ dis,
                                                      int* __restrict__ rowptr,
                                                      int2* __restrict__ csr,
                                                      ushort_t* xl,
                                                      int* __restrict__ hist) {
    __shared__ int   cnt[256];
    __shared__ float degf[256];
    __shared__ int   sscan[256];
    __shared__ int   cur[256];
    __shared__ int   lh[DBINS];
    int b = blockIdx.x, tid = threadIdx.x;
    if (tid < 256) { cnt[tid] = 0; degf[tid] = 0.f; }
    lh[tid] = 0;                                  // 1024 threads, 1024 bins
    __syncthreads();
    int s = boff[b], e = (b + 1 < NB) ? boff[b + 1] : N_EDGES;
    for (int j = s + tid; j < e; j += 1024) {
        int2 r = recs[j];
        int cl = (r.x >> 17) & 255;
        atomicAdd(&cnt[cl], 1);
        atomicAdd(&degf[cl], __int_as_float(r.y));
    }
    __syncthreads();
    int c = (tid < 256) ? cnt[tid] : 0;
    if (tid < 256) {
        sscan[tid] = c;
        int node = b * 256 + tid;
        if (node < N_NODES) atomicAdd(&lh[c > (DBINS - 1) ? (DBINS - 1) : c], 1);
    }
    __syncthreads();
    if (lh[tid] > 0) atomicAdd(&hist[tid], lh[tid]);
    #pragma unroll
    for (int off = 1; off < 256; off <<= 1) {
        int t = (tid < 256 && tid >= off) ? sscan[tid - off] : 0;
        __syncthreads();
        if (tid < 256) sscan[tid] += t;
        __syncthreads();
    }
    float d = 0.f;
    if (tid < 256) {
        int rp = s + sscan[tid] - c;              // exclusive; pad nodes get == e
        rowptr[b * 256 + tid] = rp;
        cur[tid] = rp;
        d = 1.0f / sqrtf(fmaxf(1.0f + degf[tid], 1e-30f));
        dis[b * 256 + tid] = d;
    }
    __syncthreads();
    if (tid < 256) degf[tid] = d;                 // reuse as dis cache for the tail
    __syncthreads();
    // csr permutation scatter (bucket's recs are L2-warm from pass 1)
    for (int j = s + tid; j < e; j += 1024) {
        int2 r = recs[j];
        int cl = (r.x >> 17) & 255;
        int pos = atomicAdd(&cur[cl], 1);
        csr[pos] = r;                             // gather masks the local bits
    }
    // scale tail: yl = dis * xl for this bucket's 256 rows (coalesced uint4)
    int n0 = b * 256;
    for (int i = tid; i < 256 * 8; i += 1024) {   // 8 uint4 chunks per 64-ch row
        int r = i >> 3;
        int n = n0 + r;
        if (n >= N_NODES) break;                  // trailing pad rows
        uint4* p = (uint4*)(xl + (size_t)n * HID) + (i & 7);
        float d2 = degf[r];
        uint4 u = *p;
        float lo, hi;
        uint_t w0, w1, w2, w3;
        bf2f2(u.x, lo, hi); w0 = f2bf(lo * d2) | ((uint_t)f2bf(hi * d2) << 16);
        bf2f2(u.y, lo, hi); w1 = f2bf(lo * d2) | ((uint_t)f2bf(hi * d2) << 16);
        bf2f2(u.z, lo, hi); w2 = f2bf(lo * d2) | ((uint_t)f2bf(hi * d2) << 16);
        bf2f2(u.w, lo, hi); w3 = f2bf(lo * d2) | ((uint_t)f2bf(hi * d2) << 16);
        *p = make_uint4(w0, w1, w2, w3);
    }
}

// ---------- phase 3.6: descending-degree bin offsets (suffix sum of hist) ----------
__global__ __launch_bounds__(1024) void permscan_kernel(const int* __restrict__ hist,
                                                        int* __restrict__ binofs) {
    __shared__ int s[DBINS];
    int t = threadIdx.x;
    int orig = hist[DBINS - 1 - t];
    s[t] = orig;
    __syncthreads();
    for (int off = 1; off < DBINS; off <<= 1) {
        int v = (t >= off) ? s[t - off] : 0;
        __syncthreads();
        s[t] += v;
        __syncthreads();
    }
    binofs[DBINS - 1 - t] = s[t] - orig;          // Σ_{d' > d} hist[d']
}

// ---------- phase 3.7: scatter node ids into degree-sorted order ----------
__global__ __launch_bounds__(256) void permscat_kernel(const int* __restrict__ rowptr,
                                                       int* __restrict__ binofs,
                                                       int* __restrict__ nperm) {
    __shared__ int lh[DBINS];
    __shared__ int lbase[DBINS];
    int tid = threadIdx.x;
    #pragma unroll
    for (int j = 0; j < 4; ++j) lh[tid * 4 + j] = 0;
    __syncthreads();
    int n = blockIdx.x * 256 + tid;
    int deg = 0, lpos = 0;
    bool valid = (n < N_NODES);
    if (valid) {
        deg = rowptr[n + 1] - rowptr[n];
        if (deg > DBINS - 1) deg = DBINS - 1;
        lpos = atomicAdd(&lh[deg], 1);
    }
    __syncthreads();
    #pragma unroll
    for (int j = 0; j < 4; ++j) {
        int bin = tid * 4 + j;
        int cc = lh[bin];
        if (cc > 0) lbase[bin] = atomicAdd(&binofs[bin], cc);
    }
    __syncthreads();
    if (valid) nperm[lbase[deg] + lpos] = n;
}

// ---------- gather core: 16 lanes/node (2 groups of 8), contiguous-half edge split,
// 2-deep software pipeline over 4-edge blocks. ----------
__device__ __forceinline__ void gather_row16(const int2* __restrict__ csr,
                                             const ushort_t* __restrict__ xl,
                                             int base, int end, int n,
                                             int g, int c0, int lane,
                                             float4& a0, float4& a1) {
    a0 = make_float4(0.f, 0.f, 0.f, 0.f);
    a1 = make_float4(0.f, 0.f, 0.f, 0.f);
    if (g == 0) {
        ld_bf16x8(xl + (uint_t)(n * HID + c0), a0, a1);   // self-loop, weight 1
    }
    int tot  = end - base;
    int half = (tot + 1) >> 1;
    int gs   = base + (g ? half : 0);
    int m    = g ? (tot - half) : half;
    if (m > 0) {
        int last = gs + m - 1;
        int li4  = lane & 3;       // rec slot in block (lanes 4-7 mirror 0-3)
        int gb   = lane & 56;      // group base lane
        int nb   = (m + 3) >> 2;   // number of 4-edge blocks

#define BCI(r_, u0_, u1_, u2_, u3_, w0_, w1_, w2_, w3_) do {                     \
        int r0_ = __shfl((r_).x, gb + 0, 64), r1_ = __shfl((r_).x, gb + 1, 64);  \
        int r2_ = __shfl((r_).x, gb + 2, 64), r3_ = __shfl((r_).x, gb + 3, 64);  \
        w0_ = __int_as_float(__shfl((r_).y, gb + 0, 64));                         \
        w1_ = __int_as_float(__shfl((r_).y, gb + 1, 64));                         \
        w2_ = __int_as_float(__shfl((r_).y, gb + 2, 64));                         \
        w3_ = __int_as_float(__shfl((r_).y, gb + 3, 64));                         \
        u0_ = *(const uint4*)(xl + (uint_t)((r0_ & 0x1FFFF) * HID + c0));         \
        u1_ = *(const uint4*)(xl + (uint_t)((r1_ & 0x1FFFF) * HID + c0));         \
        u2_ = *(const uint4*)(xl + (uint_t)((r2_ & 0x1FFFF) * HID + c0));         \
        u3_ = *(const uint4*)(xl + (uint_t)((r3_ & 0x1FFFF) * HID + c0));         \
    } while (0)

        uint4 uA0, uA1, uA2, uA3, uB0, uB1, uB2, uB3;
        float wA0, wA1, wA2, wA3, wB0, wB1, wB2, wB3;
        int2 rA = ldrec(csr, last, gs + li4);
        int2 rB = (nb > 1) ? ldrec(csr, last, gs + 4 + li4) : rA;
        BCI(rA, uA0, uA1, uA2, uA3, wA0, wA1, wA2, wA3);   // block 0 in flight
        int blk = 0;
        while (true) {
            bool hasB  = (blk + 1 < nb);
            bool hasA2 = (blk + 2 < nb);
            if (hasA2) rA = ldrec(csr, last, gs + (blk + 2) * 4 + li4);
            if (hasB) { BCI(rB, uB0, uB1, uB2, uB3, wB0, wB1, wB2, wB3); }
            fma8(a0, a1, uA0, wA0); fma8(a0, a1, uA1, wA1);
            fma8(a0, a1, uA2, wA2); fma8(a0, a1, uA3, wA3);
            if (!hasB) break;
            bool hasB2 = (blk + 3 < nb);
            if (hasB2) rB = ldrec(csr, last, gs + (blk + 3) * 4 + li4);
            if (hasA2) { BCI(rA, uA0, uA1, uA2, uA3, wA0, wA1, wA2, wA3); }
            fma8(a0, a1, uB0, wB0); fma8(a0, a1, uB1, wB1);
            fma8(a0, a1, uB2, wB2); fma8(a0, a1, uB3, wB3);
            if (!hasA2) break;
            blk += 2;
        }
#undef BCI
    }
    // single-level reduce: combine the two 8-lane groups of this node
    a0.x += __shfl_down(a0.x, 8, 64); a0.y += __shfl_down(a0.y, 8, 64);
    a0.z += __shfl_down(a0.z, 8, 64); a0.w += __shfl_down(a0.w, 8, 64);
    a1.x += __shfl_down(a1.x, 8, 64); a1.y += __shfl_down(a1.y, 8, 64);
    a1.z += __shfl_down(a1.z, 8, 64); a1.w += __shfl_down(a1.w, 8, 64);
}

// ---------- fused gather1 + gemm2: yl2 = dis * (relu(dis*(...) + b1) @ W2) ----------
// 16 nodes per block (4 per wave, 16 lanes each), nodes drawn degree-sorted
// through nperm so each block's 16 nodes have near-equal degree (kills the
// barrier-coupled max-degree tail that capped the gather at ~53% VALUBusy).
__global__ __launch_bounds__(256) void gather_gemm2_kernel(
        const int2* __restrict__ csr, const int* __restrict__ rowptr,
        const float* __restrict__ dis, const ushort_t* __restrict__ xl,
        const float* __restrict__ W2, const float* __restrict__ b1,
        const int* __restrict__ nperm, ushort_t* __restrict__ xl2) {
    __shared__ float sW[HID * HID];     // 16 KB
    __shared__ float sh[16][HID + 4];   // pad 68: breaks row-alias on ds_write_b128
    __shared__ int   nid[16];
    int tid = threadIdx.x;
    const float4* W4  = (const float4*)W2;
    float4*       sW4 = (float4*)sW;
    #pragma unroll
    for (int i = 0; i < 4; ++i) sW4[tid + 256 * i] = W4[tid + 256 * i];

    int wv   = tid >> 6;
    int lane = tid & 63;
    int lr   = wv * 4 + (lane >> 4);     // local row 0..15
    int n    = nperm[blockIdx.x * 16 + lr];
    int g    = (lane >> 3) & 1;
    int c0   = (lane & 7) << 3;
    if ((lane & 15) == 0) nid[lr] = n;
    int base = rowptr[n], end = rowptr[n + 1];
    float d  = dis[n];
    float4 a0, a1;
    gather_row16(csr, xl, base, end, n, g, c0, lane, a0, a1);
    if (g == 0) {
        // h = relu(dis[col]*agg + b1), stored directly (no second pass)
        float4 bb0 = *(const float4*)(b1 + c0);
        float4 bb1 = *(const float4*)(b1 + c0 + 4);
        float4 h0 = make_float4(fmaxf(a0.x * d + bb0.x, 0.f), fmaxf(a0.y * d + bb0.y, 0.f),
                                fmaxf(a0.z * d + bb0.z, 0.f), fmaxf(a0.w * d + bb0.w, 0.f));
        float4 h1 = make_float4(fmaxf(a1.x * d + bb1.x, 0.f), fmaxf(a1.y * d + bb1.y, 0.f),
                                fmaxf(a1.z * d + bb1.z, 0.f), fmaxf(a1.w * d + bb1.w, 0.f));
        *(float4*)(&sh[lr][c0])     = h0;
        *(float4*)(&sh[lr][c0 + 4]) = h1;
    }
    __syncthreads();
    // gemm2: each thread computes 4 rows x 1 col; sW value reused 4x per read
    int cc = tid & 63, rq = tid >> 6;
    float acc0 = 0.f, acc1 = 0.f, acc2 = 0.f, acc3 = 0.f;
    #pragma unroll 8
    for (int k = 0; k < HID; ++k) {
        float wk = sW[k * HID + cc];
        acc0 += sh[rq * 4 + 0][k] * wk;
        acc1 += sh[rq * 4 + 1][k] * wk;
        acc2 += sh[rq * 4 + 2][k] * wk;
        acc3 += sh[rq * 4 + 3][k] * wk;
    }
    int o0 = nid[rq * 4 + 0], o1 = nid[rq * 4 + 1];
    int o2 = nid[rq * 4 + 2], o3 = nid[rq * 4 + 3];
    xl2[(size_t)o0 * HID + cc] = f2bf(acc0 * dis[o0]);
    xl2[(size_t)o1 * HID + cc] = f2bf(acc1 * dis[o1]);
    xl2[(size_t)o2 * HID + cc] = f2bf(acc2 * dis[o2]);
    xl2[(size_t)o3 * HID + cc] = f2bf(acc3 * dis[o3]);
}

// ---------- fused gather2 + pool partial: sval[n] = relu(dis*(...)+b2) . Wc ----------
__global__ __launch_bounds__(256) void gather_pool_kernel(
        const int2* __restrict__ csr, const int* __restrict__ rowptr,
        const float* __restrict__ dis, const ushort_t* __restrict__ xl,
        const float* __restrict__ b2, const float* __restrict__ Wc,
        const int* __restrict__ nperm, float* __restrict__ sval) {
    int tid  = threadIdx.x;
    int n    = nperm[(blockIdx.x * 256 + tid) >> 4];    // grid 6250 exact
    int lane = tid & 63;
    int g    = (lane >> 3) & 1;
    int c0   = (lane & 7) << 3;
    int base = rowptr[n], end = rowptr[n + 1];
    float d  = dis[n];
    float4 a0, a1;
    gather_row16(csr, xl, base, end, n, g, c0, lane, a0, a1);
    // all lanes compute (g==1 lanes produce garbage that is never read)
    float4 bb0 = *(const float4*)(b2 + c0);
    float4 bb1 = *(const float4*)(b2 + c0 + 4);
    float4 wc0 = *(const float4*)(Wc + c0);
    float4 wc1 = *(const float4*)(Wc + c0 + 4);
    float s = fmaxf(a0.x * d + bb0.x, 0.f) * wc0.x + fmaxf(a0.y * d + bb0.y, 0.f) * wc0.y
            + fmaxf(a0.z * d + bb0.z, 0.f) * wc0.z + fmaxf(a0.w * d + bb0.w, 0.f) * wc0.w
            + fmaxf(a1.x * d + bb1.x, 0.f) * wc1.x + fmaxf(a1.y * d + bb1.y, 0.f) * wc1.y
            + fmaxf(a1.z * d + bb1.z, 0.f) * wc1.z + fmaxf(a1.w * d + bb1.w, 0.f) * wc1.w;
    s += __shfl_down(s, 4, 64);
    s += __shfl_down(s, 2, 64);
    s += __shfl_down(s, 1, 64);
    if ((lane & 15) == 0) sval[n] = s;
}

// ---------- final: out[g] = mean(sval over graph range) + bc ----------
__global__ __launch_bounds__(256) void final_out_kernel(const float* __restrict__ sval,
                                                        const int* __restrict__ batch,
                                                        const float* __restrict__ bc,
                                                        float* __restrict__ out) {
    __shared__ float s[256];
    int g = blockIdx.x;   // grid N_GRAPHS
    int lo = 0, hi = N_NODES;
    while (lo < hi) { int m = (lo + hi) >> 1; if (batch[m] < g) lo = m + 1; else hi = m; }
    int start = lo;
    hi = N_NODES;
    while (lo < hi) { int m = (lo + hi) >> 1; if (batch[m] < g + 1) lo = m + 1; else hi = m; }
    int end = lo;
    float acc = 0.f;
    for (int i = start + threadIdx.x; i < end; i += 256) acc += sval[i];
    s[threadIdx.x] = acc;
    __syncthreads();
    #pragma unroll
    for (int off = 128; off > 0; off >>= 1) {
        if (threadIdx.x < off) s[threadIdx.x] += s[threadIdx.x + off];
        __syncthreads();
    }
    if (threadIdx.x == 0)
        out[g] = s[0] / fmaxf((float)(end - start), 1.0f) + bc[0];
}

extern "C" void kernel_launch(void* const* d_in, const int* in_sizes, int n_in,
                              void* d_out, int out_size, void* d_ws, size_t ws_size,
                              hipStream_t stream) {
    const float* x     = (const float*)d_in[0];
    const int*   ei    = (const int*)  d_in[1];
    const float* ew    = (const float*)d_in[2];
    const int*   batch = (const int*)  d_in[3];
    const float* W1    = (const float*)d_in[4];
    const float* b1    = (const float*)d_in[5];
    const float* W2    = (const float*)d_in[6];
    const float* b2    = (const float*)d_in[7];
    const float* Wc    = (const float*)d_in[8];
    const float* bc    = (const float*)d_in[9];
    float* out = (float*)d_out;

    const int* row = ei;
    const int* col = ei + N_EDGES;

    // workspace: identical footprint to R7 (ends at sval+N_PAD). All new arrays
    // alias dead regions:
    //   Wt     -> recs[0..32KB)        (dead after bhist_gemm1)
    //   nperm  -> recs +128KB          (recs fully dead after degcsr; permscat runs after)
    //   hist   -> xlB[0..4KB)          (xlB first written by gather_gemm2, after hist dead)
    //   binofs -> xlB[4KB..8KB)        (dead after permscat, before gather_gemm2)
    //   H      -> csr                  (dead before degcsr writes csr)
    int2*     recs   = (int2*)d_ws;                              // E int2 = 25.6 MB
    ushort_t* xlA    = (ushort_t*)(recs + N_EDGES);              // N*HID bf16
    ushort_t* xlB    = xlA + (size_t)N_NODES * HID;              // N*HID bf16
    int2*     csr    = (int2*)(xlB + (size_t)N_NODES * HID);     // E int2
    int*      rowptr = (int*)(csr + N_EDGES);                    // N_PAD
    float*    dis    = (float*)(rowptr + N_PAD);                 // N_PAD
    int*      bsum   = (int*)(dis + N_PAD);                      // 512
    int*      boff   = bsum + 512;                               // 512
    float*    sval   = (float*)(boff + 512);                     // N_PAD
    int*      H      = (int*)csr;                                // NB*NBLK ints = 401 KB
    ushort_t* Wt     = (ushort_t*)recs;                          // 2 x [64][128] bf16 = 32 KB
    int*      nperm  = (int*)recs + 32768;                       // 400 KB at +128 KB
    int*      hist   = (int*)xlB;                                // 4 KB
    int*      binofs = hist + DBINS;                             // 4 KB

    wtprep_kernel   <<<32,   256, 0, stream>>>(W1, Wt, hist);
    bhist_gemm1_kernel<<<NBLK + G1BLK, 256, 0, stream>>>(col, H, x, Wt, xlA);
    scan1_kernel    <<<NB,   256, 0, stream>>>(H, bsum);
    bscatter_kernel <<<NBLK, 256, 0, stream>>>(row, col, ew, H, bsum, boff, recs);
    degcsr_kernel   <<<NB,  1024, 0, stream>>>(recs, boff, dis, rowptr, csr, xlA, hist);
    permscan_kernel <<<1,   1024, 0, stream>>>(hist, binofs);
    permscat_kernel <<<NB,   256, 0, stream>>>(rowptr, binofs, nperm);
    gather_gemm2_kernel<<<N_NODES / 16, 256, 0, stream>>>(csr, rowptr, dis, xlA, W2, b1, nperm, xlB);
    gather_pool_kernel <<<N_NODES / 16, 256, 0, stream>>>(csr, rowptr, dis, xlB, b2, Wc, nperm, sval);
    final_out_kernel<<<N_GRAPHS, 256, 0, stream>>>(sval, batch, bc, out);
}

// Round 11
// 341.501 us; speedup vs baseline: 1.0667x; 1.0667x over previous
//
#include <hip/hip_runtime.h>

#define N_NODES 100000
#define N_PAD   100352        // 392*256
#define N_EDGES 3200000
#define IN_DIM  128
#define HID     64
#define N_GRAPHS 256
#define NB      392           // buckets of 256 dest nodes each
#define NBLK    1024          // hist/scatter blocks (25KB lrec -> 4 blocks/CU)
#define EPB     (N_EDGES / NBLK)   // 3125
#define G1ROWS  64                 // rows per gemm1 block (MFMA tile)
#define G1BLK   (N_PAD / G1ROWS)   // 1568 gemm1 blocks

typedef unsigned short ushort_t;
typedef unsigned int   uint_t;
typedef __attribute__((ext_vector_type(4))) float f32x4;
typedef __attribute__((ext_vector_type(8))) short bf16x8;

// bf16 helpers: storage-only compression of the gathered operand
__device__ __forceinline__ ushort_t f2bf(float v) {          // round-to-nearest-even
    uint_t b = __float_as_uint(v);
    b += 0x7fffu + ((b >> 16) & 1u);
    return (ushort_t)(b >> 16);
}
__device__ __forceinline__ void bf2f2(uint_t u, float& lo, float& hi) {
    lo = __uint_as_float(u << 16);
    hi = __uint_as_float(u & 0xffff0000u);
}
// 16B load -> 8 floats
__device__ __forceinline__ void ld_bf16x8(const ushort_t* p, float4& a, float4& b) {
    uint4 u = *(const uint4*)p;
    bf2f2(u.x, a.x, a.y); bf2f2(u.y, a.z, a.w);
    bf2f2(u.z, b.x, b.y); bf2f2(u.w, b.z, b.w);
}
// unpack a loaded uint4 (8 bf16) and FMA into the accumulators with weight w
__device__ __forceinline__ void fma8(float4& a0, float4& a1, const uint4& u, float w) {
    float lo, hi;
    bf2f2(u.x, lo, hi); a0.x += lo * w; a0.y += hi * w;
    bf2f2(u.y, lo, hi); a0.z += lo * w; a0.w += hi * w;
    bf2f2(u.z, lo, hi); a1.x += lo * w; a1.y += hi * w;
    bf2f2(u.w, lo, hi); a1.z += lo * w; a1.w += hi * w;
}
// clamped edge-record load: pad slots re-read the last valid record with weight 0
__device__ __forceinline__ int2 ldrec(const int2* __restrict__ csr, int last, int idx) {
    int2 r = csr[idx <= last ? idx : last];
    if (idx > last) r.y = 0;
    return r;
}

// ---------- phase 0: W1 -> transposed split-bf16 planes Wt_hi/Wt_lo [64][128] ----------
// Whi = bf16(W), Wlo = bf16(W - Whi): two-MFMA accumulation makes W effectively
// ~16-bit-mantissa exact; only bf16(x) rounding is added vs the fp32 path.
__global__ __launch_bounds__(256) void wtprep_kernel(const float* __restrict__ W1,
                                                     ushort_t* __restrict__ Wt) {
    int i = blockIdx.x * 256 + threadIdx.x;      // 0..8191, i = k*64 + c
    int k = i >> 6, c = i & 63;
    float w = W1[i];
    ushort_t hi = f2bf(w);
    float rem = w - __uint_as_float((uint_t)hi << 16);
    ushort_t lo = f2bf(rem);
    Wt[c * 128 + k]        = hi;                 // Wt_hi [64][128]
    Wt[8192 + c * 128 + k] = lo;                 // Wt_lo [64][128]
}

// ---------- phase 1 (fused): bucket histogram (blocks 0..NBLK-1) + MFMA gemm1 ----------
__global__ __launch_bounds__(256) void bhist_gemm1_kernel(
        const int* __restrict__ col, int* __restrict__ H,
        const float* __restrict__ x, const ushort_t* __restrict__ Wt,
        ushort_t* __restrict__ xl) {
    __shared__ char smem[49152];       // hist: 3.1KB | gemm: sA 16K + sBh 16K + sBl 16K
    int tid = threadIdx.x;
    if (blockIdx.x < NBLK) {
        int (*h)[NB] = (int (*)[NB])smem;
        for (int i = tid; i < NB; i += 256) { h[0][i] = 0; h[1][i] = 0; }
        __syncthreads();
        int base = blockIdx.x * EPB;
        int sel = tid & 1;
        for (int j = tid; j < EPB; j += 256) {
            int c = col[base + j];
            atomicAdd(&h[sel][c >> 8], 1);
        }
        __syncthreads();
        for (int i = tid; i < NB; i += 256) H[i * NBLK + blockIdx.x] = h[0][i] + h[1][i];
    } else {
        int bid = blockIdx.x - NBLK;
        ushort_t* sA  = (ushort_t*)smem;          // [64][128] bf16, swizzled
        ushort_t* sBh = sA + 8192;                // [64][128] bf16, swizzled
        ushort_t* sBl = sBh + 8192;
        int r0 = bid * G1ROWS;
        // stage A: thread t -> row t>>2, 32-col chunk (t&3)*32; fp32 -> bf16
        {
            int row = tid >> 2;
            int ck  = (tid & 3) * 32;
            int gr  = r0 + row; if (gr >= N_NODES) gr = 0;     // pad rows: dummy data
            const float4* xs = (const float4*)(x + (size_t)gr * IN_DIM + ck);
            #pragma unroll
            for (int j = 0; j < 4; ++j) {
                float4 a = xs[2 * j], b = xs[2 * j + 1];
                uint4 u;
                u.x = (uint_t)f2bf(a.x) | ((uint_t)f2bf(a.y) << 16);
                u.y = (uint_t)f2bf(a.z) | ((uint_t)f2bf(a.w) << 16);
                u.z = (uint_t)f2bf(b.x) | ((uint_t)f2bf(b.y) << 16);
                u.w = (uint_t)f2bf(b.z) | ((uint_t)f2bf(b.w) << 16);
                int byte = (row * 256 + ck * 2 + j * 16) ^ ((row & 7) << 4);
                *(uint4*)(smem + byte) = u;
            }
            // stage B planes: linear 16B units -> swizzled LDS
            const uint4* wh = (const uint4*)Wt;
            const uint4* wl = (const uint4*)(Wt + 8192);
            #pragma unroll
            for (int j = 0; j < 4; ++j) {
                int u16  = tid * 4 + j;                 // 0..1023
                int colb = u16 >> 4, kc = u16 & 15;
                int byte = (colb * 256 + kc * 16) ^ ((colb & 7) << 4);
                *(uint4*)((char*)sBh + byte) = wh[u16];
                *(uint4*)((char*)sBl + byte) = wl[u16];
            }
        }
        __syncthreads();
        int wv   = tid >> 6, lane = tid & 63;
        int m0   = wv * 16;
        int fr   = lane & 15;
        int fkb  = (lane >> 4) * 16;       // byte offset of k-slice (8 bf16)
        int arow = m0 + fr;
        int aswz = (arow & 7) << 4;
        int bswz = (fr & 7) << 4;
        f32x4 acc0 = {0.f, 0.f, 0.f, 0.f}, acc1 = acc0, acc2 = acc0, acc3 = acc0;
        #pragma unroll
        for (int ks = 0; ks < 4; ++ks) {
            int kb = ks * 64 + fkb;
            bf16x8 af = *(const bf16x8*)((const char*)sA + ((arow * 256 + kb) ^ aswz));
#define BSTEP(ACC, n0) { \
            int bb = (((n0 + fr) * 256 + kb) ^ bswz); \
            bf16x8 bh = *(const bf16x8*)((const char*)sBh + bb); \
            bf16x8 bl = *(const bf16x8*)((const char*)sBl + bb); \
            ACC = __builtin_amdgcn_mfma_f32_16x16x32_bf16(af, bh, ACC, 0, 0, 0); \
            ACC = __builtin_amdgcn_mfma_f32_16x16x32_bf16(af, bl, ACC, 0, 0, 0); }
            BSTEP(acc0, 0) BSTEP(acc1, 16) BSTEP(acc2, 32) BSTEP(acc3, 48)
#undef BSTEP
        }
        // transpose D through LDS (stride 72 bf16), then 2 coalesced uint4 stores
        __syncthreads();                           // all MFMA LDS reads done
        ushort_t* sO = (ushort_t*)smem;            // [64][72] bf16 = 9216 B
        int orow = m0 + (lane >> 4) * 4;
#define TSTORE(reg) { ushort_t* sp = sO + (orow + reg) * 72; \
        sp[fr]      = f2bf(acc0[reg]); sp[fr + 16] = f2bf(acc1[reg]); \
        sp[fr + 32] = f2bf(acc2[reg]); sp[fr + 48] = f2bf(acc3[reg]); }
        TSTORE(0) TSTORE(1) TSTORE(2) TSTORE(3)
#undef TSTORE
        __syncthreads();
        int r  = tid >> 2;                         // 0..63
        int cb = (tid & 3) * 16;                   // col 0/16/32/48
        int gr2 = r0 + r;
        if (gr2 < N_NODES) {
            const uint4* sp = (const uint4*)(sO + r * 72 + cb);
            uint4* dp = (uint4*)(xl + (size_t)gr2 * HID + cb);
            dp[0] = sp[0];
            dp[1] = sp[1];
        }
    }
}

// ---------- phase 2: exclusive scan of H (NB*NBLK, bucket-major), 1024-wide ----------
__global__ __launch_bounds__(1024) void scan1_kernel(int* H, int* __restrict__ bsum) {
    __shared__ int s[NBLK];
    int tid = threadIdx.x;
    int i = blockIdx.x * NBLK + tid;          // blockIdx.x == bucket
    int v = H[i];
    s[tid] = v;
    __syncthreads();
    #pragma unroll
    for (int off = 1; off < NBLK; off <<= 1) {
        int t = (tid >= off) ? s[tid - off] : 0;
        __syncthreads();
        s[tid] += t;
        __syncthreads();
    }
    H[i] = s[tid] - v;                              // exclusive within bucket
    if (tid == NBLK - 1) bsum[blockIdx.x] = s[NBLK - 1];  // bucket total
}

// ---------- phase 3: LDS-staged scatter — bucket-sort in LDS, coalesced burst out ----------
// rec = (row | local<<17, ew); local = col & 255 (8 bits), row < 2^17
// NBLK=1024 -> lrec 25KB -> 4 blocks/CU (16 waves) vs the old 100KB/1-block (4 waves):
// the edge pass (global loads + LDS atomics) was latency-bound at 12.5% occupancy.
__global__ __launch_bounds__(256) void bscatter_kernel(const int* __restrict__ row,
                                                       const int* __restrict__ col,
                                                       const float* __restrict__ ew,
                                                       const int* __restrict__ H,
                                                       const int* __restrict__ bsum,
                                                       int* __restrict__ boff,
                                                       int2* __restrict__ recs) {
    __shared__ int2 lrec[EPB];        // 25 KB: the block's records, bucket-sorted
    __shared__ int  lofs[NB];
    __shared__ int  hcnt[NB];
    __shared__ int  gofs[NB];
    __shared__ int  cur[NB];
    __shared__ int  s[256];
    __shared__ int  carry;
    int tid = threadIdx.x, blk = blockIdx.x;
    if (tid == 0) carry = 0;
    __syncthreads();
    for (int c = 0; c < 2; ++c) {                 // 2*256 >= NB
        int i = c * 256 + tid;
        int v = (i < NB) ? bsum[i] : 0;
        s[tid] = v;
        __syncthreads();
        #pragma unroll
        for (int off = 1; off < 256; off <<= 1) {
            int t = (tid >= off) ? s[tid - off] : 0;
            __syncthreads();
            s[tid] += t;
            __syncthreads();
        }
        if (i < NB) {
            int tb = s[tid] - v + carry;          // bucket start in recs
            int ex = H[i * NBLK + blk];
            gofs[i] = tb + ex;
            hcnt[i] = ((blk < NBLK - 1) ? H[i * NBLK + blk + 1] : v) - ex;
            if (blk == 0) boff[i] = tb;
        }
        __syncthreads();
        if (tid == 0) carry += s[255];
        __syncthreads();
    }
    if (tid == 0) carry = 0;
    __syncthreads();
    for (int c = 0; c < 2; ++c) {
        int i = c * 256 + tid;
        int v = (i < NB) ? hcnt[i] : 0;
        s[tid] = v;
        __syncthreads();
        #pragma unroll
        for (int off = 1; off < 256; off <<= 1) {
            int t = (tid >= off) ? s[tid - off] : 0;
            __syncthreads();
            s[tid] += t;
            __syncthreads();
        }
        if (i < NB) { int l = s[tid] - v + carry; lofs[i] = l; cur[i] = l; }
        __syncthreads();
        if (tid == 0) carry += s[255];
        __syncthreads();
    }
    int base = blk * EPB;
    for (int j = tid; j < EPB; j += 256) {        // scalar coalesced loads (EPB odd)
        int   r = row[base + j];
        int   c = col[base + j];
        float w = ew[base + j];
        int p = atomicAdd(&cur[c >> 8], 1);
        lrec[p] = make_int2(r | ((c & 255) << 17), __float_as_int(w));
    }
    __syncthreads();
    int wv = tid >> 6, lane = tid & 63;
    for (int i = wv; i < NB; i += 4) {
        int cnt = hcnt[i], lo = lofs[i], go = gofs[i];
        for (int k = lane; k < cnt; k += 64)
            recs[go + k] = lrec[lo + k];
    }
}

// ---------- phase 3.5 (fused): recs pass -> deg+cnt -> dis/rowptr -> csr permutation
// scatter (L2-warm) -> yl scale tail. 1024 threads (R7).
__global__ __launch_bounds__(1024) void degcsr_kernel(const int2* __restrict__ recs,
                                                      const int* __restrict__ boff,
                                                      float* __restrict__ dis,
                                                      int* __restrict__ rowptr,
                                                      int2* __restrict__ csr,
                                                      ushort_t* xl) {
    __shared__ int   cnt[256];
    __shared__ float degf[256];
    __shared__ int   sscan[256];
    __shared__ int   cur[256];
    int b = blockIdx.x, tid = threadIdx.x;
    if (tid < 256) { cnt[tid] = 0; degf[tid] = 0.f; }
    __syncthreads();
    int s = boff[b], e = (b + 1 < NB) ? boff[b + 1] : N_EDGES;
    for (int j = s + tid; j < e; j += 1024) {
        int2 r = recs[j];
        int cl = (r.x >> 17) & 255;
        atomicAdd(&cnt[cl], 1);
        atomicAdd(&degf[cl], __int_as_float(r.y));
    }
    __syncthreads();
    int c = (tid < 256) ? cnt[tid] : 0;
    if (tid < 256) sscan[tid] = c;
    __syncthreads();
    #pragma unroll
    for (int off = 1; off < 256; off <<= 1) {
        int t = (tid < 256 && tid >= off) ? sscan[tid - off] : 0;
        __syncthreads();
        if (tid < 256) sscan[tid] += t;
        __syncthreads();
    }
    float d = 0.f;
    if (tid < 256) {
        int rp = s + sscan[tid] - c;              // exclusive; pad nodes get == e
        rowptr[b * 256 + tid] = rp;
        cur[tid] = rp;
        d = 1.0f / sqrtf(fmaxf(1.0f + degf[tid], 1e-30f));
        dis[b * 256 + tid] = d;
    }
    __syncthreads();
    if (tid < 256) degf[tid] = d;                 // reuse as dis cache for the tail
    __syncthreads();
    // csr permutation scatter (bucket's recs are L2-warm from pass 1)
    for (int j = s + tid; j < e; j += 1024) {
        int2 r = recs[j];
        int cl = (r.x >> 17) & 255;
        int pos = atomicAdd(&cur[cl], 1);
        csr[pos] = r;                             // gather masks the local bits
    }
    // scale tail: yl = dis * xl for this bucket's 256 rows (coalesced uint4)
    int n0 = b * 256;
    for (int i = tid; i < 256 * 8; i += 1024) {   // 8 uint4 chunks per 64-ch row
        int r = i >> 3;
        int n = n0 + r;
        if (n >= N_NODES) break;                  // trailing pad rows
        uint4* p = (uint4*)(xl + (size_t)n * HID) + (i & 7);
        float d2 = degf[r];
        uint4 u = *p;
        float lo, hi;
        uint_t w0, w1, w2, w3;
        bf2f2(u.x, lo, hi); w0 = f2bf(lo * d2) | ((uint_t)f2bf(hi * d2) << 16);
        bf2f2(u.y, lo, hi); w1 = f2bf(lo * d2) | ((uint_t)f2bf(hi * d2) << 16);
        bf2f2(u.z, lo, hi); w2 = f2bf(lo * d2) | ((uint_t)f2bf(hi * d2) << 16);
        bf2f2(u.w, lo, hi); w3 = f2bf(lo * d2) | ((uint_t)f2bf(hi * d2) << 16);
        *p = make_uint4(w0, w1, w2, w3);
    }
}

// ---------- gather core: 16 lanes/node (2 groups of 8), contiguous-half edge split,
// 2-deep software pipeline over 4-edge blocks. ----------
__device__ __forceinline__ void gather_row16(const int2* __restrict__ csr,
                                             const ushort_t* __restrict__ xl,
                                             int base, int end, int n,
                                             int g, int c0, int lane,
                                             float4& a0, float4& a1) {
    a0 = make_float4(0.f, 0.f, 0.f, 0.f);
    a1 = make_float4(0.f, 0.f, 0.f, 0.f);
    if (g == 0) {
        ld_bf16x8(xl + (uint_t)(n * HID + c0), a0, a1);   // self-loop, weight 1
    }
    int tot  = end - base;
    int half = (tot + 1) >> 1;
    int gs   = base + (g ? half : 0);
    int m    = g ? (tot - half) : half;
    if (m > 0) {
        int last = gs + m - 1;
        int li4  = lane & 3;       // rec slot in block (lanes 4-7 mirror 0-3)
        int gb   = lane & 56;      // group base lane
        int nb   = (m + 3) >> 2;   // number of 4-edge blocks

#define BCI(r_, u0_, u1_, u2_, u3_, w0_, w1_, w2_, w3_) do {                     \
        int r0_ = __shfl((r_).x, gb + 0, 64), r1_ = __shfl((r_).x, gb + 1, 64);  \
        int r2_ = __shfl((r_).x, gb + 2, 64), r3_ = __shfl((r_).x, gb + 3, 64);  \
        w0_ = __int_as_float(__shfl((r_).y, gb + 0, 64));                         \
        w1_ = __int_as_float(__shfl((r_).y, gb + 1, 64));                         \
        w2_ = __int_as_float(__shfl((r_).y, gb + 2, 64));                         \
        w3_ = __int_as_float(__shfl((r_).y, gb + 3, 64));                         \
        u0_ = *(const uint4*)(xl + (uint_t)((r0_ & 0x1FFFF) * HID + c0));         \
        u1_ = *(const uint4*)(xl + (uint_t)((r1_ & 0x1FFFF) * HID + c0));         \
        u2_ = *(const uint4*)(xl + (uint_t)((r2_ & 0x1FFFF) * HID + c0));         \
        u3_ = *(const uint4*)(xl + (uint_t)((r3_ & 0x1FFFF) * HID + c0));         \
    } while (0)

        uint4 uA0, uA1, uA2, uA3, uB0, uB1, uB2, uB3;
        float wA0, wA1, wA2, wA3, wB0, wB1, wB2, wB3;
        int2 rA = ldrec(csr, last, gs + li4);
        int2 rB = (nb > 1) ? ldrec(csr, last, gs + 4 + li4) : rA;
        BCI(rA, uA0, uA1, uA2, uA3, wA0, wA1, wA2, wA3);   // block 0 in flight
        int blk = 0;
        while (true) {
            bool hasB  = (blk + 1 < nb);
            bool hasA2 = (blk + 2 < nb);
            if (hasA2) rA = ldrec(csr, last, gs + (blk + 2) * 4 + li4);
            if (hasB) { BCI(rB, uB0, uB1, uB2, uB3, wB0, wB1, wB2, wB3); }
            fma8(a0, a1, uA0, wA0); fma8(a0, a1, uA1, wA1);
            fma8(a0, a1, uA2, wA2); fma8(a0, a1, uA3, wA3);
            if (!hasB) break;
            bool hasB2 = (blk + 3 < nb);
            if (hasB2) rB = ldrec(csr, last, gs + (blk + 3) * 4 + li4);
            if (hasA2) { BCI(rA, uA0, uA1, uA2, uA3, wA0, wA1, wA2, wA3); }
            fma8(a0, a1, uB0, wB0); fma8(a0, a1, uB1, wB1);
            fma8(a0, a1, uB2, wB2); fma8(a0, a1, uB3, wB3);
            if (!hasA2) break;
            blk += 2;
        }
#undef BCI
    }
    // single-level reduce: combine the two 8-lane groups of this node
    a0.x += __shfl_down(a0.x, 8, 64); a0.y += __shfl_down(a0.y, 8, 64);
    a0.z += __shfl_down(a0.z, 8, 64); a0.w += __shfl_down(a0.w, 8, 64);
    a1.x += __shfl_down(a1.x, 8, 64); a1.y += __shfl_down(a1.y, 8, 64);
    a1.z += __shfl_down(a1.z, 8, 64); a1.w += __shfl_down(a1.w, 8, 64);
}

// ---------- fused gather1 + gemm2: yl2 = dis * (relu(dis*(...) + b1) @ W2) ----------
// 16 nodes per block (4 per wave, 16 lanes each).
__global__ __launch_bounds__(256) void gather_gemm2_kernel(
        const int2* __restrict__ csr, const int* __restrict__ rowptr,
        const float* __restrict__ dis, const ushort_t* __restrict__ xl,
        const float* __restrict__ W2, const float* __restrict__ b1,
        ushort_t* __restrict__ xl2) {
    __shared__ float sW[HID * HID];     // 16 KB
    __shared__ float sh[16][HID + 4];   // pad 68: breaks row-alias on ds_write_b128
    int tid = threadIdx.x;
    const float4* W4  = (const float4*)W2;
    float4*       sW4 = (float4*)sW;
    #pragma unroll
    for (int i = 0; i < 4; ++i) sW4[tid + 256 * i] = W4[tid + 256 * i];

    int n0   = blockIdx.x * 16;
    int wv   = tid >> 6;
    int lane = tid & 63;
    int lr   = wv * 4 + (lane >> 4);     // local row 0..15
    int n    = n0 + lr;
    int g    = (lane >> 3) & 1;
    int c0   = (lane & 7) << 3;
    int base = rowptr[n], end = rowptr[n + 1];
    float d  = dis[n];
    float4 a0, a1;
    gather_row16(csr, xl, base, end, n, g, c0, lane, a0, a1);
    if (g == 0) {
        // h = relu(dis[col]*agg + b1), stored directly (no second pass)
        float4 bb0 = *(const float4*)(b1 + c0);
        float4 bb1 = *(const float4*)(b1 + c0 + 4);
        float4 h0 = make_float4(fmaxf(a0.x * d + bb0.x, 0.f), fmaxf(a0.y * d + bb0.y, 0.f),
                                fmaxf(a0.z * d + bb0.z, 0.f), fmaxf(a0.w * d + bb0.w, 0.f));
        float4 h1 = make_float4(fmaxf(a1.x * d + bb1.x, 0.f), fmaxf(a1.y * d + bb1.y, 0.f),
                                fmaxf(a1.z * d + bb1.z, 0.f), fmaxf(a1.w * d + bb1.w, 0.f));
        *(float4*)(&sh[lr][c0])     = h0;
        *(float4*)(&sh[lr][c0 + 4]) = h1;
    }
    __syncthreads();
    // gemm2: each thread computes 4 rows x 1 col; sW value reused 4x per read
    int cc = tid & 63, rq = tid >> 6;
    float acc0 = 0.f, acc1 = 0.f, acc2 = 0.f, acc3 = 0.f;
    #pragma unroll 8
    for (int k = 0; k < HID; ++k) {
        float wk = sW[k * HID + cc];
        acc0 += sh[rq * 4 + 0][k] * wk;
        acc1 += sh[rq * 4 + 1][k] * wk;
        acc2 += sh[rq * 4 + 2][k] * wk;
        acc3 += sh[rq * 4 + 3][k] * wk;
    }
    xl2[(size_t)(n0 + rq * 4 + 0) * HID + cc] = f2bf(acc0 * dis[n0 + rq * 4 + 0]);
    xl2[(size_t)(n0 + rq * 4 + 1) * HID + cc] = f2bf(acc1 * dis[n0 + rq * 4 + 1]);
    xl2[(size_t)(n0 + rq * 4 + 2) * HID + cc] = f2bf(acc2 * dis[n0 + rq * 4 + 2]);
    xl2[(size_t)(n0 + rq * 4 + 3) * HID + cc] = f2bf(acc3 * dis[n0 + rq * 4 + 3]);
}

// ---------- fused gather2 + pool partial: sval[n] = relu(dis*(...)+b2) . Wc ----------
__global__ __launch_bounds__(256) void gather_pool_kernel(
        const int2* __restrict__ csr, const int* __restrict__ rowptr,
        const float* __restrict__ dis, const ushort_t* __restrict__ xl,
        const float* __restrict__ b2, const float* __restrict__ Wc,
        float* __restrict__ sval) {
    int tid  = threadIdx.x;
    int n    = (blockIdx.x * 256 + tid) >> 4;           // grid 6250 exact
    int lane = tid & 63;
    int g    = (lane >> 3) & 1;
    int c0   = (lane & 7) << 3;
    int base = rowptr[n], end = rowptr[n + 1];
    float d  = dis[n];
    float4 a0, a1;
    gather_row16(csr, xl, base, end, n, g, c0, lane, a0, a1);
    // all lanes compute (g==1 lanes produce garbage that is never read)
    float4 bb0 = *(const float4*)(b2 + c0);
    float4 bb1 = *(const float4*)(b2 + c0 + 4);
    float4 wc0 = *(const float4*)(Wc + c0);
    float4 wc1 = *(const float4*)(Wc + c0 + 4);
    float s = fmaxf(a0.x * d + bb0.x, 0.f) * wc0.x + fmaxf(a0.y * d + bb0.y, 0.f) * wc0.y
            + fmaxf(a0.z * d + bb0.z, 0.f) * wc0.z + fmaxf(a0.w * d + bb0.w, 0.f) * wc0.w
            + fmaxf(a1.x * d + bb1.x, 0.f) * wc1.x + fmaxf(a1.y * d + bb1.y, 0.f) * wc1.y
            + fmaxf(a1.z * d + bb1.z, 0.f) * wc1.z + fmaxf(a1.w * d + bb1.w, 0.f) * wc1.w;
    s += __shfl_down(s, 4, 64);
    s += __shfl_down(s, 2, 64);
    s += __shfl_down(s, 1, 64);
    if ((lane & 15) == 0) sval[n] = s;
}

// ---------- final: out[g] = mean(sval over graph range) + bc ----------
__global__ __launch_bounds__(256) void final_out_kernel(const float* __restrict__ sval,
                                                        const int* __restrict__ batch,
                                                        const float* __restrict__ bc,
                                                        float* __restrict__ out) {
    __shared__ float s[256];
    int g = blockIdx.x;   // grid N_GRAPHS
    int lo = 0, hi = N_NODES;
    while (lo < hi) { int m = (lo + hi) >> 1; if (batch[m] < g) lo = m + 1; else hi = m; }
    int start = lo;
    hi = N_NODES;
    while (lo < hi) { int m = (lo + hi) >> 1; if (batch[m] < g + 1) lo = m + 1; else hi = m; }
    int end = lo;
    float acc = 0.f;
    for (int i = start + threadIdx.x; i < end; i += 256) acc += sval[i];
    s[threadIdx.x] = acc;
    __syncthreads();
    #pragma unroll
    for (int off = 128; off > 0; off >>= 1) {
        if (threadIdx.x < off) s[threadIdx.x] += s[threadIdx.x + off];
        __syncthreads();
    }
    if (threadIdx.x == 0)
        out[g] = s[0] / fmaxf((float)(end - start), 1.0f) + bc[0];
}

extern "C" void kernel_launch(void* const* d_in, const int* in_sizes, int n_in,
                              void* d_out, int out_size, void* d_ws, size_t ws_size,
                              hipStream_t stream) {
    const float* x     = (const float*)d_in[0];
    const int*   ei    = (const int*)  d_in[1];
    const float* ew    = (const float*)d_in[2];
    const int*   batch = (const int*)  d_in[3];
    const float* W1    = (const float*)d_in[4];
    const float* b1    = (const float*)d_in[5];
    const float* W2    = (const float*)d_in[6];
    const float* b2    = (const float*)d_in[7];
    const float* Wc    = (const float*)d_in[8];
    const float* bc    = (const float*)d_in[9];
    float* out = (float*)d_out;

    const int* row = ei;
    const int* col = ei + N_EDGES;

    // workspace (R7 footprint, ends at sval+N_PAD): recs | xlA | xlB | csr |
    // rowptr | dis | bsum | boff | sval.
    // H aliases csr (1.6MB, dead before degcsr writes csr). Wt aliases recs.
    int2*     recs   = (int2*)d_ws;                              // E int2 = 25.6 MB
    ushort_t* xlA    = (ushort_t*)(recs + N_EDGES);              // N*HID bf16
    ushort_t* xlB    = xlA + (size_t)N_NODES * HID;              // N*HID bf16
    int2*     csr    = (int2*)(xlB + (size_t)N_NODES * HID);     // E int2
    int*      rowptr = (int*)(csr + N_EDGES);                    // N_PAD
    float*    dis    = (float*)(rowptr + N_PAD);                 // N_PAD
    int*      bsum   = (int*)(dis + N_PAD);                      // 512
    int*      boff   = bsum + 512;                               // 512
    float*    sval   = (float*)(boff + 512);                     // N_PAD
    int*      H      = (int*)csr;                                // NB*NBLK ints = 1.6 MB
    ushort_t* Wt     = (ushort_t*)recs;                          // 2 x [64][128] bf16 = 32 KB

    wtprep_kernel   <<<32,   256, 0, stream>>>(W1, Wt);
    bhist_gemm1_kernel<<<NBLK + G1BLK, 256, 0, stream>>>(col, H, x, Wt, xlA);
    scan1_kernel    <<<NB,  1024, 0, stream>>>(H, bsum);
    bscatter_kernel <<<NBLK, 256, 0, stream>>>(row, col, ew, H, bsum, boff, recs);
    degcsr_kernel   <<<NB,  1024, 0, stream>>>(recs, boff, dis, rowptr, csr, xlA);
    gather_gemm2_kernel<<<N_NODES / 16, 256, 0, stream>>>(csr, rowptr, dis, xlA, W2, b1, xlB);
    gather_pool_kernel <<<N_NODES / 16, 256, 0, stream>>>(csr, rowptr, dis, xlB, b2, Wc, sval);
    final_out_kernel<<<N_GRAPHS, 256, 0, stream>>>(sval, batch, bc, out);
}

// Round 12
// 333.231 us; speedup vs baseline: 1.0932x; 1.0248x over previous
//
#include <hip/hip_runtime.h>

#define N_NODES 100000
#define N_PAD   100352        // 392*256
#define N_EDGES 3200000
#define IN_DIM  128
#define HID     64
#define N_GRAPHS 256
#define NB      392           // buckets of 256 dest nodes each
#define NBLK    1024          // hist/scatter blocks (25KB lrec -> 4 blocks/CU)
#define EPB     (N_EDGES / NBLK)   // 3125
#define G1ROWS  64                 // rows per gemm1 block (MFMA tile)
#define G1BLK   (N_PAD / G1ROWS)   // 1568 gemm1 blocks

typedef unsigned short ushort_t;
typedef unsigned int   uint_t;
typedef __attribute__((ext_vector_type(4))) float f32x4;
typedef __attribute__((ext_vector_type(8))) short bf16x8;

// bf16 helpers: storage-only compression of the gathered operand
__device__ __forceinline__ ushort_t f2bf(float v) {          // round-to-nearest-even
    uint_t b = __float_as_uint(v);
    b += 0x7fffu + ((b >> 16) & 1u);
    return (ushort_t)(b >> 16);
}
__device__ __forceinline__ void bf2f2(uint_t u, float& lo, float& hi) {
    lo = __uint_as_float(u << 16);
    hi = __uint_as_float(u & 0xffff0000u);
}
// 16B load -> 8 floats
__device__ __forceinline__ void ld_bf16x8(const ushort_t* p, float4& a, float4& b) {
    uint4 u = *(const uint4*)p;
    bf2f2(u.x, a.x, a.y); bf2f2(u.y, a.z, a.w);
    bf2f2(u.z, b.x, b.y); bf2f2(u.w, b.z, b.w);
}
// unpack a loaded uint4 (8 bf16) and FMA into the accumulators with weight w
__device__ __forceinline__ void fma8(float4& a0, float4& a1, const uint4& u, float w) {
    float lo, hi;
    bf2f2(u.x, lo, hi); a0.x += lo * w; a0.y += hi * w;
    bf2f2(u.y, lo, hi); a0.z += lo * w; a0.w += hi * w;
    bf2f2(u.z, lo, hi); a1.x += lo * w; a1.y += hi * w;
    bf2f2(u.w, lo, hi); a1.z += lo * w; a1.w += hi * w;
}
// clamped edge-record load: pad slots re-read the last valid record with weight 0
__device__ __forceinline__ int2 ldrec(const int2* __restrict__ csr, int last, int idx) {
    int2 r = csr[idx <= last ? idx : last];
    if (idx > last) r.y = 0;
    return r;
}

// ---------- phase 0: W1 -> transposed split-bf16 planes Wt_hi/Wt_lo [64][128] ----------
// Whi = bf16(W), Wlo = bf16(W - Whi): two-MFMA accumulation makes W effectively
// ~16-bit-mantissa exact; only bf16(x) rounding is added vs the fp32 path.
__global__ __launch_bounds__(256) void wtprep_kernel(const float* __restrict__ W1,
                                                     ushort_t* __restrict__ Wt) {
    int i = blockIdx.x * 256 + threadIdx.x;      // 0..8191, i = k*64 + c
    int k = i >> 6, c = i & 63;
    float w = W1[i];
    ushort_t hi = f2bf(w);
    float rem = w - __uint_as_float((uint_t)hi << 16);
    ushort_t lo = f2bf(rem);
    Wt[c * 128 + k]        = hi;                 // Wt_hi [64][128]
    Wt[8192 + c * 128 + k] = lo;                 // Wt_lo [64][128]
}

// ---------- phase 1 (fused): bucket histogram (blocks 0..NBLK-1) + MFMA gemm1 ----------
__global__ __launch_bounds__(256) void bhist_gemm1_kernel(
        const int* __restrict__ col, int* __restrict__ H,
        const float* __restrict__ x, const ushort_t* __restrict__ Wt,
        ushort_t* __restrict__ xl) {
    __shared__ char smem[49152];       // hist: 3.1KB | gemm: sA 16K + sBh 16K + sBl 16K
    int tid = threadIdx.x;
    if (blockIdx.x < NBLK) {
        int (*h)[NB] = (int (*)[NB])smem;
        for (int i = tid; i < NB; i += 256) { h[0][i] = 0; h[1][i] = 0; }
        __syncthreads();
        int base = blockIdx.x * EPB;
        int sel = tid & 1;
        for (int j = tid; j < EPB; j += 256) {
            int c = col[base + j];
            atomicAdd(&h[sel][c >> 8], 1);
        }
        __syncthreads();
        for (int i = tid; i < NB; i += 256) H[i * NBLK + blockIdx.x] = h[0][i] + h[1][i];
    } else {
        int bid = blockIdx.x - NBLK;
        ushort_t* sA  = (ushort_t*)smem;          // [64][128] bf16, swizzled
        ushort_t* sBh = sA + 8192;                // [64][128] bf16, swizzled
        ushort_t* sBl = sBh + 8192;
        int r0 = bid * G1ROWS;
        // stage A: thread t -> row t>>2, 32-col chunk (t&3)*32; fp32 -> bf16
        {
            int row = tid >> 2;
            int ck  = (tid & 3) * 32;
            int gr  = r0 + row; if (gr >= N_NODES) gr = 0;     // pad rows: dummy data
            const float4* xs = (const float4*)(x + (size_t)gr * IN_DIM + ck);
            #pragma unroll
            for (int j = 0; j < 4; ++j) {
                float4 a = xs[2 * j], b = xs[2 * j + 1];
                uint4 u;
                u.x = (uint_t)f2bf(a.x) | ((uint_t)f2bf(a.y) << 16);
                u.y = (uint_t)f2bf(a.z) | ((uint_t)f2bf(a.w) << 16);
                u.z = (uint_t)f2bf(b.x) | ((uint_t)f2bf(b.y) << 16);
                u.w = (uint_t)f2bf(b.z) | ((uint_t)f2bf(b.w) << 16);
                int byte = (row * 256 + ck * 2 + j * 16) ^ ((row & 7) << 4);
                *(uint4*)(smem + byte) = u;
            }
            // stage B planes: linear 16B units -> swizzled LDS
            const uint4* wh = (const uint4*)Wt;
            const uint4* wl = (const uint4*)(Wt + 8192);
            #pragma unroll
            for (int j = 0; j < 4; ++j) {
                int u16  = tid * 4 + j;                 // 0..1023
                int colb = u16 >> 4, kc = u16 & 15;
                int byte = (colb * 256 + kc * 16) ^ ((colb & 7) << 4);
                *(uint4*)((char*)sBh + byte) = wh[u16];
                *(uint4*)((char*)sBl + byte) = wl[u16];
            }
        }
        __syncthreads();
        int wv   = tid >> 6, lane = tid & 63;
        int m0   = wv * 16;
        int fr   = lane & 15;
        int fkb  = (lane >> 4) * 16;       // byte offset of k-slice (8 bf16)
        int arow = m0 + fr;
        int aswz = (arow & 7) << 4;
        int bswz = (fr & 7) << 4;
        f32x4 acc0 = {0.f, 0.f, 0.f, 0.f}, acc1 = acc0, acc2 = acc0, acc3 = acc0;
        #pragma unroll
        for (int ks = 0; ks < 4; ++ks) {
            int kb = ks * 64 + fkb;
            bf16x8 af = *(const bf16x8*)((const char*)sA + ((arow * 256 + kb) ^ aswz));
#define BSTEP(ACC, n0) { \
            int bb = (((n0 + fr) * 256 + kb) ^ bswz); \
            bf16x8 bh = *(const bf16x8*)((const char*)sBh + bb); \
            bf16x8 bl = *(const bf16x8*)((const char*)sBl + bb); \
            ACC = __builtin_amdgcn_mfma_f32_16x16x32_bf16(af, bh, ACC, 0, 0, 0); \
            ACC = __builtin_amdgcn_mfma_f32_16x16x32_bf16(af, bl, ACC, 0, 0, 0); }
            BSTEP(acc0, 0) BSTEP(acc1, 16) BSTEP(acc2, 32) BSTEP(acc3, 48)
#undef BSTEP
        }
        // transpose D through LDS (stride 72 bf16), then 2 coalesced uint4 stores
        __syncthreads();                           // all MFMA LDS reads done
        ushort_t* sO = (ushort_t*)smem;            // [64][72] bf16 = 9216 B
        int orow = m0 + (lane >> 4) * 4;
#define TSTORE(reg) { ushort_t* sp = sO + (orow + reg) * 72; \
        sp[fr]      = f2bf(acc0[reg]); sp[fr + 16] = f2bf(acc1[reg]); \
        sp[fr + 32] = f2bf(acc2[reg]); sp[fr + 48] = f2bf(acc3[reg]); }
        TSTORE(0) TSTORE(1) TSTORE(2) TSTORE(3)
#undef TSTORE
        __syncthreads();
        int r  = tid >> 2;                         // 0..63
        int cb = (tid & 3) * 16;                   // col 0/16/32/48
        int gr2 = r0 + r;
        if (gr2 < N_NODES) {
            const uint4* sp = (const uint4*)(sO + r * 72 + cb);
            uint4* dp = (uint4*)(xl + (size_t)gr2 * HID + cb);
            dp[0] = sp[0];
            dp[1] = sp[1];
        }
    }
}

// ---------- phase 2: exclusive scan of H (NB*NBLK, bucket-major), 1024-wide ----------
__global__ __launch_bounds__(1024) void scan1_kernel(int* H, int* __restrict__ bsum) {
    __shared__ int s[NBLK];
    int tid = threadIdx.x;
    int i = blockIdx.x * NBLK + tid;          // blockIdx.x == bucket
    int v = H[i];
    s[tid] = v;
    __syncthreads();
    #pragma unroll
    for (int off = 1; off < NBLK; off <<= 1) {
        int t = (tid >= off) ? s[tid - off] : 0;
        __syncthreads();
        s[tid] += t;
        __syncthreads();
    }
    H[i] = s[tid] - v;                              // exclusive within bucket
    if (tid == NBLK - 1) bsum[blockIdx.x] = s[NBLK - 1];  // bucket total
}

// ---------- phase 3: LDS-staged scatter — bucket-sort in LDS, coalesced burst out ----------
// rec = (row | local<<17, ew); local = col & 255 (8 bits), row < 2^17
// Burst-out is 8-lane-group-per-bucket: per-(bucket,block) cnt ~ 8 at NBLK=1024,
// so a 64-lane-per-bucket stride left 87% of lanes idle for 98 iterations.
__global__ __launch_bounds__(256) void bscatter_kernel(const int* __restrict__ row,
                                                       const int* __restrict__ col,
                                                       const float* __restrict__ ew,
                                                       const int* __restrict__ H,
                                                       const int* __restrict__ bsum,
                                                       int* __restrict__ boff,
                                                       int2* __restrict__ recs) {
    __shared__ int2 lrec[EPB];        // 25 KB: the block's records, bucket-sorted
    __shared__ int  lofs[NB];
    __shared__ int  hcnt[NB];
    __shared__ int  gofs[NB];
    __shared__ int  cur[NB];
    __shared__ int  s[256];
    __shared__ int  carry;
    int tid = threadIdx.x, blk = blockIdx.x;
    if (tid == 0) carry = 0;
    __syncthreads();
    for (int c = 0; c < 2; ++c) {                 // 2*256 >= NB
        int i = c * 256 + tid;
        int v = (i < NB) ? bsum[i] : 0;
        s[tid] = v;
        __syncthreads();
        #pragma unroll
        for (int off = 1; off < 256; off <<= 1) {
            int t = (tid >= off) ? s[tid - off] : 0;
            __syncthreads();
            s[tid] += t;
            __syncthreads();
        }
        if (i < NB) {
            int tb = s[tid] - v + carry;          // bucket start in recs
            int ex = H[i * NBLK + blk];
            gofs[i] = tb + ex;
            hcnt[i] = ((blk < NBLK - 1) ? H[i * NBLK + blk + 1] : v) - ex;
            if (blk == 0) boff[i] = tb;
        }
        __syncthreads();
        if (tid == 0) carry += s[255];
        __syncthreads();
    }
    if (tid == 0) carry = 0;
    __syncthreads();
    for (int c = 0; c < 2; ++c) {
        int i = c * 256 + tid;
        int v = (i < NB) ? hcnt[i] : 0;
        s[tid] = v;
        __syncthreads();
        #pragma unroll
        for (int off = 1; off < 256; off <<= 1) {
            int t = (tid >= off) ? s[tid - off] : 0;
            __syncthreads();
            s[tid] += t;
            __syncthreads();
        }
        if (i < NB) { int l = s[tid] - v + carry; lofs[i] = l; cur[i] = l; }
        __syncthreads();
        if (tid == 0) carry += s[255];
        __syncthreads();
    }
    int base = blk * EPB;
    for (int j = tid; j < EPB; j += 256) {        // scalar coalesced loads (EPB odd)
        int   r = row[base + j];
        int   c = col[base + j];
        float w = ew[base + j];
        int p = atomicAdd(&cur[c >> 8], 1);
        lrec[p] = make_int2(r | ((c & 255) << 17), __float_as_int(w));
    }
    __syncthreads();
    int grp = tid >> 3, gl = tid & 7;             // 32 groups of 8 lanes
    for (int i = grp; i < NB; i += 32) {
        int cnt = hcnt[i], lo = lofs[i], go = gofs[i];
        for (int k = gl; k < cnt; k += 8)
            recs[go + k] = lrec[lo + k];
    }
}

// ---------- phase 3.5 (fused): recs pass -> deg+cnt -> dis/rowptr -> csr permutation
// scatter (L2-warm) -> yl scale tail. 1024 threads (R7).
__global__ __launch_bounds__(1024) void degcsr_kernel(const int2* __restrict__ recs,
                                                      const int* __restrict__ boff,
                                                      float* __restrict__ dis,
                                                      int* __restrict__ rowptr,
                                                      int2* __restrict__ csr,
                                                      ushort_t* xl) {
    __shared__ int   cnt[256];
    __shared__ float degf[256];
    __shared__ int   sscan[256];
    __shared__ int   cur[256];
    int b = blockIdx.x, tid = threadIdx.x;
    if (tid < 256) { cnt[tid] = 0; degf[tid] = 0.f; }
    __syncthreads();
    int s = boff[b], e = (b + 1 < NB) ? boff[b + 1] : N_EDGES;
    for (int j = s + tid; j < e; j += 1024) {
        int2 r = recs[j];
        int cl = (r.x >> 17) & 255;
        atomicAdd(&cnt[cl], 1);
        atomicAdd(&degf[cl], __int_as_float(r.y));
    }
    __syncthreads();
    int c = (tid < 256) ? cnt[tid] : 0;
    if (tid < 256) sscan[tid] = c;
    __syncthreads();
    #pragma unroll
    for (int off = 1; off < 256; off <<= 1) {
        int t = (tid < 256 && tid >= off) ? sscan[tid - off] : 0;
        __syncthreads();
        if (tid < 256) sscan[tid] += t;
        __syncthreads();
    }
    float d = 0.f;
    if (tid < 256) {
        int rp = s + sscan[tid] - c;              // exclusive; pad nodes get == e
        rowptr[b * 256 + tid] = rp;
        cur[tid] = rp;
        d = 1.0f / sqrtf(fmaxf(1.0f + degf[tid], 1e-30f));
        dis[b * 256 + tid] = d;
    }
    __syncthreads();
    if (tid < 256) degf[tid] = d;                 // reuse as dis cache for the tail
    __syncthreads();
    // csr permutation scatter (bucket's recs are L2-warm from pass 1)
    for (int j = s + tid; j < e; j += 1024) {
        int2 r = recs[j];
        int cl = (r.x >> 17) & 255;
        int pos = atomicAdd(&cur[cl], 1);
        csr[pos] = r;                             // gather masks the local bits
    }
    // scale tail: yl = dis * xl for this bucket's 256 rows (coalesced uint4)
    int n0 = b * 256;
    for (int i = tid; i < 256 * 8; i += 1024) {   // 8 uint4 chunks per 64-ch row
        int r = i >> 3;
        int n = n0 + r;
        if (n >= N_NODES) break;                  // trailing pad rows
        uint4* p = (uint4*)(xl + (size_t)n * HID) + (i & 7);
        float d2 = degf[r];
        uint4 u = *p;
        float lo, hi;
        uint_t w0, w1, w2, w3;
        bf2f2(u.x, lo, hi); w0 = f2bf(lo * d2) | ((uint_t)f2bf(hi * d2) << 16);
        bf2f2(u.y, lo, hi); w1 = f2bf(lo * d2) | ((uint_t)f2bf(hi * d2) << 16);
        bf2f2(u.z, lo, hi); w2 = f2bf(lo * d2) | ((uint_t)f2bf(hi * d2) << 16);
        bf2f2(u.w, lo, hi); w3 = f2bf(lo * d2) | ((uint_t)f2bf(hi * d2) << 16);
        *p = make_uint4(w0, w1, w2, w3);
    }
}

// ---------- gather core: 16 lanes/node (2 groups of 8), contiguous-half edge split,
// 2-deep software pipeline over 4-edge blocks. ----------
__device__ __forceinline__ void gather_row16(const int2* __restrict__ csr,
                                             const ushort_t* __restrict__ xl,
                                             int base, int end, int n,
                                             int g, int c0, int lane,
                                             float4& a0, float4& a1) {
    a0 = make_float4(0.f, 0.f, 0.f, 0.f);
    a1 = make_float4(0.f, 0.f, 0.f, 0.f);
    if (g == 0) {
        ld_bf16x8(xl + (uint_t)(n * HID + c0), a0, a1);   // self-loop, weight 1
    }
    int tot  = end - base;
    int half = (tot + 1) >> 1;
    int gs   = base + (g ? half : 0);
    int m    = g ? (tot - half) : half;
    if (m > 0) {
        int last = gs + m - 1;
        int li4  = lane & 3;       // rec slot in block (lanes 4-7 mirror 0-3)
        int gb   = lane & 56;      // group base lane
        int nb   = (m + 3) >> 2;   // number of 4-edge blocks

#define BCI(r_, u0_, u1_, u2_, u3_, w0_, w1_, w2_, w3_) do {                     \
        int r0_ = __shfl((r_).x, gb + 0, 64), r1_ = __shfl((r_).x, gb + 1, 64);  \
        int r2_ = __shfl((r_).x, gb + 2, 64), r3_ = __shfl((r_).x, gb + 3, 64);  \
        w0_ = __int_as_float(__shfl((r_).y, gb + 0, 64));                         \
        w1_ = __int_as_float(__shfl((r_).y, gb + 1, 64));                         \
        w2_ = __int_as_float(__shfl((r_).y, gb + 2, 64));                         \
        w3_ = __int_as_float(__shfl((r_).y, gb + 3, 64));                         \
        u0_ = *(const uint4*)(xl + (uint_t)((r0_ & 0x1FFFF) * HID + c0));         \
        u1_ = *(const uint4*)(xl + (uint_t)((r1_ & 0x1FFFF) * HID + c0));         \
        u2_ = *(const uint4*)(xl + (uint_t)((r2_ & 0x1FFFF) * HID + c0));         \
        u3_ = *(const uint4*)(xl + (uint_t)((r3_ & 0x1FFFF) * HID + c0));         \
    } while (0)

        uint4 uA0, uA1, uA2, uA3, uB0, uB1, uB2, uB3;
        float wA0, wA1, wA2, wA3, wB0, wB1, wB2, wB3;
        int2 rA = ldrec(csr, last, gs + li4);
        int2 rB = (nb > 1) ? ldrec(csr, last, gs + 4 + li4) : rA;
        BCI(rA, uA0, uA1, uA2, uA3, wA0, wA1, wA2, wA3);   // block 0 in flight
        int blk = 0;
        while (true) {
            bool hasB  = (blk + 1 < nb);
            bool hasA2 = (blk + 2 < nb);
            if (hasA2) rA = ldrec(csr, last, gs + (blk + 2) * 4 + li4);
            if (hasB) { BCI(rB, uB0, uB1, uB2, uB3, wB0, wB1, wB2, wB3); }
            fma8(a0, a1, uA0, wA0); fma8(a0, a1, uA1, wA1);
            fma8(a0, a1, uA2, wA2); fma8(a0, a1, uA3, wA3);
            if (!hasB) break;
            bool hasB2 = (blk + 3 < nb);
            if (hasB2) rB = ldrec(csr, last, gs + (blk + 3) * 4 + li4);
            if (hasA2) { BCI(rA, uA0, uA1, uA2, uA3, wA0, wA1, wA2, wA3); }
            fma8(a0, a1, uB0, wB0); fma8(a0, a1, uB1, wB1);
            fma8(a0, a1, uB2, wB2); fma8(a0, a1, uB3, wB3);
            if (!hasA2) break;
            blk += 2;
        }
#undef BCI
    }
    // single-level reduce: combine the two 8-lane groups of this node
    a0.x += __shfl_down(a0.x, 8, 64); a0.y += __shfl_down(a0.y, 8, 64);
    a0.z += __shfl_down(a0.z, 8, 64); a0.w += __shfl_down(a0.w, 8, 64);
    a1.x += __shfl_down(a1.x, 8, 64); a1.y += __shfl_down(a1.y, 8, 64);
    a1.z += __shfl_down(a1.z, 8, 64); a1.w += __shfl_down(a1.w, 8, 64);
}

// ---------- fused gather1 + gemm2: yl2 = dis * (relu(dis*(...) + b1) @ W2) ----------
// 16 nodes per block (4 per wave, 16 lanes each).
__global__ __launch_bounds__(256) void gather_gemm2_kernel(
        const int2* __restrict__ csr, const int* __restrict__ rowptr,
        const float* __restrict__ dis, const ushort_t* __restrict__ xl,
        const float* __restrict__ W2, const float* __restrict__ b1,
        ushort_t* __restrict__ xl2) {
    __shared__ float sW[HID * HID];     // 16 KB
    __shared__ float sh[16][HID + 4];   // pad 68: breaks row-alias on ds_write_b128
    int tid = threadIdx.x;
    const float4* W4  = (const float4*)W2;
    float4*       sW4 = (float4*)sW;
    #pragma unroll
    for (int i = 0; i < 4; ++i) sW4[tid + 256 * i] = W4[tid + 256 * i];

    int n0   = blockIdx.x * 16;
    int wv   = tid >> 6;
    int lane = tid & 63;
    int lr   = wv * 4 + (lane >> 4);     // local row 0..15
    int n    = n0 + lr;
    int g    = (lane >> 3) & 1;
    int c0   = (lane & 7) << 3;
    int base = rowptr[n], end = rowptr[n + 1];
    float d  = dis[n];
    float4 a0, a1;
    gather_row16(csr, xl, base, end, n, g, c0, lane, a0, a1);
    if (g == 0) {
        // h = relu(dis[col]*agg + b1), stored directly (no second pass)
        float4 bb0 = *(const float4*)(b1 + c0);
        float4 bb1 = *(const float4*)(b1 + c0 + 4);
        float4 h0 = make_float4(fmaxf(a0.x * d + bb0.x, 0.f), fmaxf(a0.y * d + bb0.y, 0.f),
                                fmaxf(a0.z * d + bb0.z, 0.f), fmaxf(a0.w * d + bb0.w, 0.f));
        float4 h1 = make_float4(fmaxf(a1.x * d + bb1.x, 0.f), fmaxf(a1.y * d + bb1.y, 0.f),
                                fmaxf(a1.z * d + bb1.z, 0.f), fmaxf(a1.w * d + bb1.w, 0.f));
        *(float4*)(&sh[lr][c0])     = h0;
        *(float4*)(&sh[lr][c0 + 4]) = h1;
    }
    __syncthreads();
    // gemm2: each thread computes 4 rows x 1 col; sW value reused 4x per read
    int cc = tid & 63, rq = tid >> 6;
    float acc0 = 0.f, acc1 = 0.f, acc2 = 0.f, acc3 = 0.f;
    #pragma unroll 8
    for (int k = 0; k < HID; ++k) {
        float wk = sW[k * HID + cc];
        acc0 += sh[rq * 4 + 0][k] * wk;
        acc1 += sh[rq * 4 + 1][k] * wk;
        acc2 += sh[rq * 4 + 2][k] * wk;
        acc3 += sh[rq * 4 + 3][k] * wk;
    }
    xl2[(size_t)(n0 + rq * 4 + 0) * HID + cc] = f2bf(acc0 * dis[n0 + rq * 4 + 0]);
    xl2[(size_t)(n0 + rq * 4 + 1) * HID + cc] = f2bf(acc1 * dis[n0 + rq * 4 + 1]);
    xl2[(size_t)(n0 + rq * 4 + 2) * HID + cc] = f2bf(acc2 * dis[n0 + rq * 4 + 2]);
    xl2[(size_t)(n0 + rq * 4 + 3) * HID + cc] = f2bf(acc3 * dis[n0 + rq * 4 + 3]);
}

// ---------- fused gather2 + pool partial: sval[n] = relu(dis*(...)+b2) . Wc ----------
__global__ __launch_bounds__(256) void gather_pool_kernel(
        const int2* __restrict__ csr, const int* __restrict__ rowptr,
        const float* __restrict__ dis, const ushort_t* __restrict__ xl,
        const float* __restrict__ b2, const float* __restrict__ Wc,
        float* __restrict__ sval) {
    int tid  = threadIdx.x;
    int n    = (blockIdx.x * 256 + tid) >> 4;           // grid 6250 exact
    int lane = tid & 63;
    int g    = (lane >> 3) & 1;
    int c0   = (lane & 7) << 3;
    int base = rowptr[n], end = rowptr[n + 1];
    float d  = dis[n];
    float4 a0, a1;
    gather_row16(csr, xl, base, end, n, g, c0, lane, a0, a1);
    // all lanes compute (g==1 lanes produce garbage that is never read)
    float4 bb0 = *(const float4*)(b2 + c0);
    float4 bb1 = *(const float4*)(b2 + c0 + 4);
    float4 wc0 = *(const float4*)(Wc + c0);
    float4 wc1 = *(const float4*)(Wc + c0 + 4);
    float s = fmaxf(a0.x * d + bb0.x, 0.f) * wc0.x + fmaxf(a0.y * d + bb0.y, 0.f) * wc0.y
            + fmaxf(a0.z * d + bb0.z, 0.f) * wc0.z + fmaxf(a0.w * d + bb0.w, 0.f) * wc0.w
            + fmaxf(a1.x * d + bb1.x, 0.f) * wc1.x + fmaxf(a1.y * d + bb1.y, 0.f) * wc1.y
            + fmaxf(a1.z * d + bb1.z, 0.f) * wc1.z + fmaxf(a1.w * d + bb1.w, 0.f) * wc1.w;
    s += __shfl_down(s, 4, 64);
    s += __shfl_down(s, 2, 64);
    s += __shfl_down(s, 1, 64);
    if ((lane & 15) == 0) sval[n] = s;
}

// ---------- final: out[g] = mean(sval over graph range) + bc ----------
__global__ __launch_bounds__(256) void final_out_kernel(const float* __restrict__ sval,
                                                        const int* __restrict__ batch,
                                                        const float* __restrict__ bc,
                                                        float* __restrict__ out) {
    __shared__ float s[256];
    int g = blockIdx.x;   // grid N_GRAPHS
    int lo = 0, hi = N_NODES;
    while (lo < hi) { int m = (lo + hi) >> 1; if (batch[m] < g) lo = m + 1; else hi = m; }
    int start = lo;
    hi = N_NODES;
    while (lo < hi) { int m = (lo + hi) >> 1; if (batch[m] < g + 1) lo = m + 1; else hi = m; }
    int end = lo;
    float acc = 0.f;
    for (int i = start + threadIdx.x; i < end; i += 256) acc += sval[i];
    s[threadIdx.x] = acc;
    __syncthreads();
    #pragma unroll
    for (int off = 128; off > 0; off >>= 1) {
        if (threadIdx.x < off) s[threadIdx.x] += s[threadIdx.x + off];
        __syncthreads();
    }
    if (threadIdx.x == 0)
        out[g] = s[0] / fmaxf((float)(end - start), 1.0f) + bc[0];
}

extern "C" void kernel_launch(void* const* d_in, const int* in_sizes, int n_in,
                              void* d_out, int out_size, void* d_ws, size_t ws_size,
                              hipStream_t stream) {
    const float* x     = (const float*)d_in[0];
    const int*   ei    = (const int*)  d_in[1];
    const float* ew    = (const float*)d_in[2];
    const int*   batch = (const int*)  d_in[3];
    const float* W1    = (const float*)d_in[4];
    const float* b1    = (const float*)d_in[5];
    const float* W2    = (const float*)d_in[6];
    const float* b2    = (const float*)d_in[7];
    const float* Wc    = (const float*)d_in[8];
    const float* bc    = (const float*)d_in[9];
    float* out = (float*)d_out;

    const int* row = ei;
    const int* col = ei + N_EDGES;

    // workspace (R7 footprint, ends at sval+N_PAD): recs | xlA | xlB | csr |
    // rowptr | dis | bsum | boff | sval.
    // H aliases csr (1.6MB, dead before degcsr writes csr). Wt aliases recs.
    int2*     recs   = (int2*)d_ws;                              // E int2 = 25.6 MB
    ushort_t* xlA    = (ushort_t*)(recs + N_EDGES);              // N*HID bf16
    ushort_t* xlB    = xlA + (size_t)N_NODES * HID;              // N*HID bf16
    int2*     csr    = (int2*)(xlB + (size_t)N_NODES * HID);     // E int2
    int*      rowptr = (int*)(csr + N_EDGES);                    // N_PAD
    float*    dis    = (float*)(rowptr + N_PAD);                 // N_PAD
    int*      bsum   = (int*)(dis + N_PAD);                      // 512
    int*      boff   = bsum + 512;                               // 512
    float*    sval   = (float*)(boff + 512);                     // N_PAD
    int*      H      = (int*)csr;                                // NB*NBLK ints = 1.6 MB
    ushort_t* Wt     = (ushort_t*)recs;                          // 2 x [64][128] bf16 = 32 KB

    wtprep_kernel   <<<32,   256, 0, stream>>>(W1, Wt);
    bhist_gemm1_kernel<<<NBLK + G1BLK, 256, 0, stream>>>(col, H, x, Wt, xlA);
    scan1_kernel    <<<NB,  1024, 0, stream>>>(H, bsum);
    bscatter_kernel <<<NBLK, 256, 0, stream>>>(row, col, ew, H, bsum, boff, recs);
    degcsr_kernel   <<<NB,  1024, 0, stream>>>(recs, boff, dis, rowptr, csr, xlA);
    gather_gemm2_kernel<<<N_NODES / 16, 256, 0, stream>>>(csr, rowptr, dis, xlA, W2, b1, xlB);
    gather_pool_kernel <<<N_NODES / 16, 256, 0, stream>>>(csr, rowptr, dis, xlB, b2, Wc, sval);
    final_out_kernel<<<N_GRAPHS, 256, 0, stream>>>(sval, batch, bc, out);
}

// Round 13
// 311.422 us; speedup vs baseline: 1.1697x; 1.0700x over previous
//
#include <hip/hip_runtime.h>

#define N_NODES 100000
#define N_PAD   100352        // 392*256
#define N_EDGES 3200000
#define IN_DIM  128
#define HID     64
#define N_GRAPHS 256
#define NB      392           // buckets of 256 dest nodes each
#define NBLK    1024          // hist/scatter blocks (25KB lrec -> 4 blocks/CU)
#define EPB     (N_EDGES / NBLK)   // 3125
#define G1ROWS  64                 // rows per gemm1 block (MFMA tile)
#define G1BLK   (N_PAD / G1ROWS)   // 1568 gemm1 blocks

typedef unsigned short ushort_t;
typedef unsigned int   uint_t;
typedef unsigned char  uchar_t;
typedef __attribute__((ext_vector_type(4))) float f32x4;
typedef __attribute__((ext_vector_type(2))) float f32x2;
typedef __attribute__((ext_vector_type(8))) short bf16x8;

// bf16 helpers
__device__ __forceinline__ ushort_t f2bf(float v) {          // round-to-nearest-even
    uint_t b = __float_as_uint(v);
    b += 0x7fffu + ((b >> 16) & 1u);
    return (ushort_t)(b >> 16);
}
__device__ __forceinline__ void bf2f2(uint_t u, float& lo, float& hi) {
    lo = __uint_as_float(u << 16);
    hi = __uint_as_float(u & 0xffff0000u);
}
// fp8 e4m3 (OCP) helpers — values stored with x16 scale; consumers fold 1/16 into dis
__device__ __forceinline__ uint_t pk4fp8(float f0, float f1, float f2, float f3) {
    uint_t p = __builtin_amdgcn_cvt_pk_fp8_f32(f0, f1, 0, false);
    p = __builtin_amdgcn_cvt_pk_fp8_f32(f2, f3, p, true);
    return p;
}
__device__ __forceinline__ uchar_t fp8enc(float v) {
    return (uchar_t)(__builtin_amdgcn_cvt_pk_fp8_f32(v, 0.f, 0, false) & 0xFF);
}
// unpack 8 fp8 (uint2) and FMA into accumulators with weight w
__device__ __forceinline__ void fma8f8(float4& a0, float4& a1, const uint2& u, float w) {
    f32x2 p;
    p = __builtin_amdgcn_cvt_pk_f32_fp8(u.x, false); a0.x += p[0] * w; a0.y += p[1] * w;
    p = __builtin_amdgcn_cvt_pk_f32_fp8(u.x, true);  a0.z += p[0] * w; a0.w += p[1] * w;
    p = __builtin_amdgcn_cvt_pk_f32_fp8(u.y, false); a1.x += p[0] * w; a1.y += p[1] * w;
    p = __builtin_amdgcn_cvt_pk_f32_fp8(u.y, true);  a1.z += p[0] * w; a1.w += p[1] * w;
}
// clamped edge-record load: pad slots re-read the last valid record with weight 0
__device__ __forceinline__ int2 ldrec(const int2* __restrict__ csr, int last, int idx) {
    int2 r = csr[idx <= last ? idx : last];
    if (idx > last) r.y = 0;
    return r;
}

// ---------- phase 0: W1 -> transposed split-bf16 planes Wt_hi/Wt_lo [64][128] ----------
__global__ __launch_bounds__(256) void wtprep_kernel(const float* __restrict__ W1,
                                                     ushort_t* __restrict__ Wt) {
    int i = blockIdx.x * 256 + threadIdx.x;      // 0..8191, i = k*64 + c
    int k = i >> 6, c = i & 63;
    float w = W1[i];
    ushort_t hi = f2bf(w);
    float rem = w - __uint_as_float((uint_t)hi << 16);
    ushort_t lo = f2bf(rem);
    Wt[c * 128 + k]        = hi;                 // Wt_hi [64][128]
    Wt[8192 + c * 128 + k] = lo;                 // Wt_lo [64][128]
}

// ---------- phase 1 (fused): bucket histogram (blocks 0..NBLK-1) + MFMA gemm1 ----------
__global__ __launch_bounds__(256) void bhist_gemm1_kernel(
        const int* __restrict__ col, int* __restrict__ H,
        const float* __restrict__ x, const ushort_t* __restrict__ Wt,
        ushort_t* __restrict__ xl) {
    __shared__ char smem[49152];       // hist: 3.1KB | gemm: sA 16K + sBh 16K + sBl 16K
    int tid = threadIdx.x;
    if (blockIdx.x < NBLK) {
        int (*h)[NB] = (int (*)[NB])smem;
        for (int i = tid; i < NB; i += 256) { h[0][i] = 0; h[1][i] = 0; }
        __syncthreads();
        int base = blockIdx.x * EPB;
        int sel = tid & 1;
        for (int j = tid; j < EPB; j += 256) {
            int c = col[base + j];
            atomicAdd(&h[sel][c >> 8], 1);
        }
        __syncthreads();
        for (int i = tid; i < NB; i += 256) H[i * NBLK + blockIdx.x] = h[0][i] + h[1][i];
    } else {
        int bid = blockIdx.x - NBLK;
        ushort_t* sA  = (ushort_t*)smem;          // [64][128] bf16, swizzled
        ushort_t* sBh = sA + 8192;                // [64][128] bf16, swizzled
        ushort_t* sBl = sBh + 8192;
        int r0 = bid * G1ROWS;
        // stage A: thread t -> row t>>2, 32-col chunk (t&3)*32; fp32 -> bf16
        {
            int row = tid >> 2;
            int ck  = (tid & 3) * 32;
            int gr  = r0 + row; if (gr >= N_NODES) gr = 0;     // pad rows: dummy data
            const float4* xs = (const float4*)(x + (size_t)gr * IN_DIM + ck);
            #pragma unroll
            for (int j = 0; j < 4; ++j) {
                float4 a = xs[2 * j], b = xs[2 * j + 1];
                uint4 u;
                u.x = (uint_t)f2bf(a.x) | ((uint_t)f2bf(a.y) << 16);
                u.y = (uint_t)f2bf(a.z) | ((uint_t)f2bf(a.w) << 16);
                u.z = (uint_t)f2bf(b.x) | ((uint_t)f2bf(b.y) << 16);
                u.w = (uint_t)f2bf(b.z) | ((uint_t)f2bf(b.w) << 16);
                int byte = (row * 256 + ck * 2 + j * 16) ^ ((row & 7) << 4);
                *(uint4*)(smem + byte) = u;
            }
            // stage B planes: linear 16B units -> swizzled LDS
            const uint4* wh = (const uint4*)Wt;
            const uint4* wl = (const uint4*)(Wt + 8192);
            #pragma unroll
            for (int j = 0; j < 4; ++j) {
                int u16  = tid * 4 + j;                 // 0..1023
                int colb = u16 >> 4, kc = u16 & 15;
                int byte = (colb * 256 + kc * 16) ^ ((colb & 7) << 4);
                *(uint4*)((char*)sBh + byte) = wh[u16];
                *(uint4*)((char*)sBl + byte) = wl[u16];
            }
        }
        __syncthreads();
        int wv   = tid >> 6, lane = tid & 63;
        int m0   = wv * 16;
        int fr   = lane & 15;
        int fkb  = (lane >> 4) * 16;       // byte offset of k-slice (8 bf16)
        int arow = m0 + fr;
        int aswz = (arow & 7) << 4;
        int bswz = (fr & 7) << 4;
        f32x4 acc0 = {0.f, 0.f, 0.f, 0.f}, acc1 = acc0, acc2 = acc0, acc3 = acc0;
        #pragma unroll
        for (int ks = 0; ks < 4; ++ks) {
            int kb = ks * 64 + fkb;
            bf16x8 af = *(const bf16x8*)((const char*)sA + ((arow * 256 + kb) ^ aswz));
#define BSTEP(ACC, n0) { \
            int bb = (((n0 + fr) * 256 + kb) ^ bswz); \
            bf16x8 bh = *(const bf16x8*)((const char*)sBh + bb); \
            bf16x8 bl = *(const bf16x8*)((const char*)sBl + bb); \
            ACC = __builtin_amdgcn_mfma_f32_16x16x32_bf16(af, bh, ACC, 0, 0, 0); \
            ACC = __builtin_amdgcn_mfma_f32_16x16x32_bf16(af, bl, ACC, 0, 0, 0); }
            BSTEP(acc0, 0) BSTEP(acc1, 16) BSTEP(acc2, 32) BSTEP(acc3, 48)
#undef BSTEP
        }
        // transpose D through LDS (stride 72 bf16), then 2 coalesced uint4 stores
        __syncthreads();                           // all MFMA LDS reads done
        ushort_t* sO = (ushort_t*)smem;            // [64][72] bf16 = 9216 B
        int orow = m0 + (lane >> 4) * 4;
#define TSTORE(reg) { ushort_t* sp = sO + (orow + reg) * 72; \
        sp[fr]      = f2bf(acc0[reg]); sp[fr + 16] = f2bf(acc1[reg]); \
        sp[fr + 32] = f2bf(acc2[reg]); sp[fr + 48] = f2bf(acc3[reg]); }
        TSTORE(0) TSTORE(1) TSTORE(2) TSTORE(3)
#undef TSTORE
        __syncthreads();
        int r  = tid >> 2;                         // 0..63
        int cb = (tid & 3) * 16;                   // col 0/16/32/48
        int gr2 = r0 + r;
        if (gr2 < N_NODES) {
            const uint4* sp = (const uint4*)(sO + r * 72 + cb);
            uint4* dp = (uint4*)(xl + (size_t)gr2 * HID + cb);
            dp[0] = sp[0];
            dp[1] = sp[1];
        }
    }
}

// ---------- phase 2: exclusive scan of H (NB*NBLK, bucket-major), 1024-wide ----------
__global__ __launch_bounds__(1024) void scan1_kernel(int* H, int* __restrict__ bsum) {
    __shared__ int s[NBLK];
    int tid = threadIdx.x;
    int i = blockIdx.x * NBLK + tid;          // blockIdx.x == bucket
    int v = H[i];
    s[tid] = v;
    __syncthreads();
    #pragma unroll
    for (int off = 1; off < NBLK; off <<= 1) {
        int t = (tid >= off) ? s[tid - off] : 0;
        __syncthreads();
        s[tid] += t;
        __syncthreads();
    }
    H[i] = s[tid] - v;                              // exclusive within bucket
    if (tid == NBLK - 1) bsum[blockIdx.x] = s[NBLK - 1];  // bucket total
}

// ---------- phase 3: LDS-staged scatter — bucket-sort in LDS, coalesced burst out ----------
// rec = (row | local<<17, ew); local = col & 255 (8 bits), row < 2^17
__global__ __launch_bounds__(256) void bscatter_kernel(const int* __restrict__ row,
                                                       const int* __restrict__ col,
                                                       const float* __restrict__ ew,
                                                       const int* __restrict__ H,
                                                       const int* __restrict__ bsum,
                                                       int* __restrict__ boff,
                                                       int2* __restrict__ recs) {
    __shared__ int2 lrec[EPB];        // 25 KB: the block's records, bucket-sorted
    __shared__ int  lofs[NB];
    __shared__ int  hcnt[NB];
    __shared__ int  gofs[NB];
    __shared__ int  cur[NB];
    __shared__ int  s[256];
    __shared__ int  carry;
    int tid = threadIdx.x, blk = blockIdx.x;
    if (tid == 0) carry = 0;
    __syncthreads();
    for (int c = 0; c < 2; ++c) {                 // 2*256 >= NB
        int i = c * 256 + tid;
        int v = (i < NB) ? bsum[i] : 0;
        s[tid] = v;
        __syncthreads();
        #pragma unroll
        for (int off = 1; off < 256; off <<= 1) {
            int t = (tid >= off) ? s[tid - off] : 0;
            __syncthreads();
            s[tid] += t;
            __syncthreads();
        }
        if (i < NB) {
            int tb = s[tid] - v + carry;          // bucket start in recs
            int ex = H[i * NBLK + blk];
            gofs[i] = tb + ex;
            hcnt[i] = ((blk < NBLK - 1) ? H[i * NBLK + blk + 1] : v) - ex;
            if (blk == 0) boff[i] = tb;
        }
        __syncthreads();
        if (tid == 0) carry += s[255];
        __syncthreads();
    }
    if (tid == 0) carry = 0;
    __syncthreads();
    for (int c = 0; c < 2; ++c) {
        int i = c * 256 + tid;
        int v = (i < NB) ? hcnt[i] : 0;
        s[tid] = v;
        __syncthreads();
        #pragma unroll
        for (int off = 1; off < 256; off <<= 1) {
            int t = (tid >= off) ? s[tid - off] : 0;
            __syncthreads();
            s[tid] += t;
            __syncthreads();
        }
        if (i < NB) { int l = s[tid] - v + carry; lofs[i] = l; cur[i] = l; }
        __syncthreads();
        if (tid == 0) carry += s[255];
        __syncthreads();
    }
    int base = blk * EPB;
    for (int j = tid; j < EPB; j += 256) {        // scalar coalesced loads (EPB odd)
        int   r = row[base + j];
        int   c = col[base + j];
        float w = ew[base + j];
        int p = atomicAdd(&cur[c >> 8], 1);
        lrec[p] = make_int2(r | ((c & 255) << 17), __float_as_int(w));
    }
    __syncthreads();
    int grp = tid >> 3, gl = tid & 7;             // 32 groups of 8 lanes
    for (int i = grp; i < NB; i += 32) {
        int cnt = hcnt[i], lo = lofs[i], go = gofs[i];
        for (int k = gl; k < cnt; k += 8)
            recs[go + k] = lrec[lo + k];
    }
}

// ---------- phase 3.5 (fused): recs pass -> deg+cnt -> dis/rowptr -> csr permutation
// scatter (L2-warm) -> fp8 scale tail: xl8A[n] = fp8(16 * dis[n] * xl[n]).
__global__ __launch_bounds__(1024) void degcsr_kernel(const int2* __restrict__ recs,
                                                      const int* __restrict__ boff,
                                                      float* __restrict__ dis,
                                                      int* __restrict__ rowptr,
                                                      int2* __restrict__ csr,
                                                      const ushort_t* __restrict__ xl,
                                                      uchar_t* __restrict__ xl8) {
    __shared__ int   cnt[256];
    __shared__ float degf[256];
    __shared__ int   sscan[256];
    __shared__ int   cur[256];
    int b = blockIdx.x, tid = threadIdx.x;
    if (tid < 256) { cnt[tid] = 0; degf[tid] = 0.f; }
    __syncthreads();
    int s = boff[b], e = (b + 1 < NB) ? boff[b + 1] : N_EDGES;
    for (int j = s + tid; j < e; j += 1024) {
        int2 r = recs[j];
        int cl = (r.x >> 17) & 255;
        atomicAdd(&cnt[cl], 1);
        atomicAdd(&degf[cl], __int_as_float(r.y));
    }
    __syncthreads();
    int c = (tid < 256) ? cnt[tid] : 0;
    if (tid < 256) sscan[tid] = c;
    __syncthreads();
    #pragma unroll
    for (int off = 1; off < 256; off <<= 1) {
        int t = (tid < 256 && tid >= off) ? sscan[tid - off] : 0;
        __syncthreads();
        if (tid < 256) sscan[tid] += t;
        __syncthreads();
    }
    float d = 0.f;
    if (tid < 256) {
        int rp = s + sscan[tid] - c;              // exclusive; pad nodes get == e
        rowptr[b * 256 + tid] = rp;
        cur[tid] = rp;
        d = 1.0f / sqrtf(fmaxf(1.0f + degf[tid], 1e-30f));
        dis[b * 256 + tid] = d;
    }
    __syncthreads();
    if (tid < 256) degf[tid] = d;                 // reuse as dis cache for the tail
    __syncthreads();
    // csr permutation scatter (bucket's recs are L2-warm from pass 1)
    for (int j = s + tid; j < e; j += 1024) {
        int2 r = recs[j];
        int cl = (r.x >> 17) & 255;
        int pos = atomicAdd(&cur[cl], 1);
        csr[pos] = r;                             // gather masks the local bits
    }
    // scale tail: xl8 = fp8(16 * dis * xl) for this bucket's 256 rows
    int n0 = b * 256;
    for (int i = tid; i < 256 * 8; i += 1024) {   // 8 bf16-uint4 chunks per row
        int r = i >> 3;
        int n = n0 + r;
        if (n >= N_NODES) break;                  // trailing pad rows
        const uint4* p = (const uint4*)(xl + (size_t)n * HID) + (i & 7);
        float d2 = degf[r] * 16.0f;
        uint4 u = *p;
        float l0, h0, l1, h1, l2, h2, l3, h3;
        bf2f2(u.x, l0, h0); bf2f2(u.y, l1, h1);
        bf2f2(u.z, l2, h2); bf2f2(u.w, l3, h3);
        uint2 o;
        o.x = pk4fp8(l0 * d2, h0 * d2, l1 * d2, h1 * d2);
        o.y = pk4fp8(l2 * d2, h2 * d2, l3 * d2, h3 * d2);
        *((uint2*)(xl8 + (size_t)n * HID) + (i & 7)) = o;   // HID bytes/row
    }
}

// ---------- gather core (fp8): 16 lanes/node (2 groups of 8), contiguous-half split,
// 2-deep pipeline over 4-edge blocks. Row loads are 8B (one cacheline per group). ----------
__device__ __forceinline__ void gather_row16(const int2* __restrict__ csr,
                                             const uchar_t* __restrict__ xl8,
                                             int base, int end, int n,
                                             int g, int c0, int lane,
                                             float4& a0, float4& a1) {
    a0 = make_float4(0.f, 0.f, 0.f, 0.f);
    a1 = make_float4(0.f, 0.f, 0.f, 0.f);
    if (g == 0) {
        uint2 u = *(const uint2*)(xl8 + (uint_t)(n * HID + c0));   // self-loop, w=1
        fma8f8(a0, a1, u, 1.0f);
    }
    int tot  = end - base;
    int half = (tot + 1) >> 1;
    int gs   = base + (g ? half : 0);
    int m    = g ? (tot - half) : half;
    if (m > 0) {
        int last = gs + m - 1;
        int li4  = lane & 3;       // rec slot in block (lanes 4-7 mirror 0-3)
        int gb   = lane & 56;      // group base lane
        int nb   = (m + 3) >> 2;   // number of 4-edge blocks

#define BCI(r_, u0_, u1_, u2_, u3_, w0_, w1_, w2_, w3_) do {                     \
        int r0_ = __shfl((r_).x, gb + 0, 64), r1_ = __shfl((r_).x, gb + 1, 64);  \
        int r2_ = __shfl((r_).x, gb + 2, 64), r3_ = __shfl((r_).x, gb + 3, 64);  \
        w0_ = __int_as_float(__shfl((r_).y, gb + 0, 64));                         \
        w1_ = __int_as_float(__shfl((r_).y, gb + 1, 64));                         \
        w2_ = __int_as_float(__shfl((r_).y, gb + 2, 64));                         \
        w3_ = __int_as_float(__shfl((r_).y, gb + 3, 64));                         \
        u0_ = *(const uint2*)(xl8 + (uint_t)((r0_ & 0x1FFFF) * HID + c0));        \
        u1_ = *(const uint2*)(xl8 + (uint_t)((r1_ & 0x1FFFF) * HID + c0));        \
        u2_ = *(const uint2*)(xl8 + (uint_t)((r2_ & 0x1FFFF) * HID + c0));        \
        u3_ = *(const uint2*)(xl8 + (uint_t)((r3_ & 0x1FFFF) * HID + c0));        \
    } while (0)

        uint2 uA0, uA1, uA2, uA3, uB0, uB1, uB2, uB3;
        float wA0, wA1, wA2, wA3, wB0, wB1, wB2, wB3;
        int2 rA = ldrec(csr, last, gs + li4);
        int2 rB = (nb > 1) ? ldrec(csr, last, gs + 4 + li4) : rA;
        BCI(rA, uA0, uA1, uA2, uA3, wA0, wA1, wA2, wA3);   // block 0 in flight
        int blk = 0;
        while (true) {
            bool hasB  = (blk + 1 < nb);
            bool hasA2 = (blk + 2 < nb);
            if (hasA2) rA = ldrec(csr, last, gs + (blk + 2) * 4 + li4);
            if (hasB) { BCI(rB, uB0, uB1, uB2, uB3, wB0, wB1, wB2, wB3); }
            fma8f8(a0, a1, uA0, wA0); fma8f8(a0, a1, uA1, wA1);
            fma8f8(a0, a1, uA2, wA2); fma8f8(a0, a1, uA3, wA3);
            if (!hasB) break;
            bool hasB2 = (blk + 3 < nb);
            if (hasB2) rB = ldrec(csr, last, gs + (blk + 3) * 4 + li4);
            if (hasA2) { BCI(rA, uA0, uA1, uA2, uA3, wA0, wA1, wA2, wA3); }
            fma8f8(a0, a1, uB0, wB0); fma8f8(a0, a1, uB1, wB1);
            fma8f8(a0, a1, uB2, wB2); fma8f8(a0, a1, uB3, wB3);
            if (!hasA2) break;
            blk += 2;
        }
#undef BCI
    }
    // single-level reduce: combine the two 8-lane groups of this node
    a0.x += __shfl_down(a0.x, 8, 64); a0.y += __shfl_down(a0.y, 8, 64);
    a0.z += __shfl_down(a0.z, 8, 64); a0.w += __shfl_down(a0.w, 8, 64);
    a1.x += __shfl_down(a1.x, 8, 64); a1.y += __shfl_down(a1.y, 8, 64);
    a1.z += __shfl_down(a1.z, 8, 64); a1.w += __shfl_down(a1.w, 8, 64);
}

// ---------- fused gather1 + gemm2: yl2 = dis * (relu(dis*(...) + b1) @ W2) ----------
// 16 nodes per block (4 per wave, 16 lanes each). fp8 in (x16), fp8 out (x16).
__global__ __launch_bounds__(256) void gather_gemm2_kernel(
        const int2* __restrict__ csr, const int* __restrict__ rowptr,
        const float* __restrict__ dis, const uchar_t* __restrict__ xl8,
        const float* __restrict__ W2, const float* __restrict__ b1,
        uchar_t* __restrict__ xl2) {
    __shared__ float sW[HID * HID];     // 16 KB
    __shared__ float sh[16][HID + 4];   // pad 68: breaks row-alias on ds_write_b128
    int tid = threadIdx.x;
    const float4* W4  = (const float4*)W2;
    float4*       sW4 = (float4*)sW;
    #pragma unroll
    for (int i = 0; i < 4; ++i) sW4[tid + 256 * i] = W4[tid + 256 * i];

    int n0   = blockIdx.x * 16;
    int wv   = tid >> 6;
    int lane = tid & 63;
    int lr   = wv * 4 + (lane >> 4);     // local row 0..15
    int n    = n0 + lr;
    int g    = (lane >> 3) & 1;
    int c0   = (lane & 7) << 3;
    int base = rowptr[n], end = rowptr[n + 1];
    float ds = dis[n] * 0.0625f;         // fold the x16 fp8 scale into dis
    float4 a0, a1;
    gather_row16(csr, xl8, base, end, n, g, c0, lane, a0, a1);
    if (g == 0) {
        // h = relu(dis[col]*agg + b1), stored directly (no second pass)
        float4 bb0 = *(const float4*)(b1 + c0);
        float4 bb1 = *(const float4*)(b1 + c0 + 4);
        float4 h0 = make_float4(fmaxf(a0.x * ds + bb0.x, 0.f), fmaxf(a0.y * ds + bb0.y, 0.f),
                                fmaxf(a0.z * ds + bb0.z, 0.f), fmaxf(a0.w * ds + bb0.w, 0.f));
        float4 h1 = make_float4(fmaxf(a1.x * ds + bb1.x, 0.f), fmaxf(a1.y * ds + bb1.y, 0.f),
                                fmaxf(a1.z * ds + bb1.z, 0.f), fmaxf(a1.w * ds + bb1.w, 0.f));
        *(float4*)(&sh[lr][c0])     = h0;
        *(float4*)(&sh[lr][c0 + 4]) = h1;
    }
    __syncthreads();
    // gemm2: each thread computes 4 rows x 1 col; sW value reused 4x per read
    int cc = tid & 63, rq = tid >> 6;
    float acc0 = 0.f, acc1 = 0.f, acc2 = 0.f, acc3 = 0.f;
    #pragma unroll 8
    for (int k = 0; k < HID; ++k) {
        float wk = sW[k * HID + cc];
        acc0 += sh[rq * 4 + 0][k] * wk;
        acc1 += sh[rq * 4 + 1][k] * wk;
        acc2 += sh[rq * 4 + 2][k] * wk;
        acc3 += sh[rq * 4 + 3][k] * wk;
    }
    int o0 = n0 + rq * 4;
    xl2[(size_t)(o0 + 0) * HID + cc] = fp8enc(acc0 * dis[o0 + 0] * 16.0f);
    xl2[(size_t)(o0 + 1) * HID + cc] = fp8enc(acc1 * dis[o0 + 1] * 16.0f);
    xl2[(size_t)(o0 + 2) * HID + cc] = fp8enc(acc2 * dis[o0 + 2] * 16.0f);
    xl2[(size_t)(o0 + 3) * HID + cc] = fp8enc(acc3 * dis[o0 + 3] * 16.0f);
}

// ---------- fused gather2 + pool partial: sval[n] = relu(dis*(...)+b2) . Wc ----------
__global__ __launch_bounds__(256) void gather_pool_kernel(
        const int2* __restrict__ csr, const int* __restrict__ rowptr,
        const float* __restrict__ dis, const uchar_t* __restrict__ xl8,
        const float* __restrict__ b2, const float* __restrict__ Wc,
        float* __restrict__ sval) {
    int tid  = threadIdx.x;
    int n    = (blockIdx.x * 256 + tid) >> 4;           // grid 6250 exact
    int lane = tid & 63;
    int g    = (lane >> 3) & 1;
    int c0   = (lane & 7) << 3;
    int base = rowptr[n], end = rowptr[n + 1];
    float ds = dis[n] * 0.0625f;                        // fold x16 fp8 scale
    float4 a0, a1;
    gather_row16(csr, xl8, base, end, n, g, c0, lane, a0, a1);
    // all lanes compute (g==1 lanes produce garbage that is never read)
    float4 bb0 = *(const float4*)(b2 + c0);
    float4 bb1 = *(const float4*)(b2 + c0 + 4);
    float4 wc0 = *(const float4*)(Wc + c0);
    float4 wc1 = *(const float4*)(Wc + c0 + 4);
    float s = fmaxf(a0.x * ds + bb0.x, 0.f) * wc0.x + fmaxf(a0.y * ds + bb0.y, 0.f) * wc0.y
            + fmaxf(a0.z * ds + bb0.z, 0.f) * wc0.z + fmaxf(a0.w * ds + bb0.w, 0.f) * wc0.w
            + fmaxf(a1.x * ds + bb1.x, 0.f) * wc1.x + fmaxf(a1.y * ds + bb1.y, 0.f) * wc1.y
            + fmaxf(a1.z * ds + bb1.z, 0.f) * wc1.z + fmaxf(a1.w * ds + bb1.w, 0.f) * wc1.w;
    s += __shfl_down(s, 4, 64);
    s += __shfl_down(s, 2, 64);
    s += __shfl_down(s, 1, 64);
    if ((lane & 15) == 0) sval[n] = s;
}

// ---------- final: out[g] = mean(sval over graph range) + bc ----------
__global__ __launch_bounds__(256) void final_out_kernel(const float* __restrict__ sval,
                                                        const int* __restrict__ batch,
                                                        const float* __restrict__ bc,
                                                        float* __restrict__ out) {
    __shared__ float s[256];
    int g = blockIdx.x;   // grid N_GRAPHS
    int lo = 0, hi = N_NODES;
    while (lo < hi) { int m = (lo + hi) >> 1; if (batch[m] < g) lo = m + 1; else hi = m; }
    int start = lo;
    hi = N_NODES;
    while (lo < hi) { int m = (lo + hi) >> 1; if (batch[m] < g + 1) lo = m + 1; else hi = m; }
    int end = lo;
    float acc = 0.f;
    for (int i = start + threadIdx.x; i < end; i += 256) acc += sval[i];
    s[threadIdx.x] = acc;
    __syncthreads();
    #pragma unroll
    for (int off = 128; off > 0; off >>= 1) {
        if (threadIdx.x < off) s[threadIdx.x] += s[threadIdx.x + off];
        __syncthreads();
    }
    if (threadIdx.x == 0)
        out[g] = s[0] / fmaxf((float)(end - start), 1.0f) + bc[0];
}

extern "C" void kernel_launch(void* const* d_in, const int* in_sizes, int n_in,
                              void* d_out, int out_size, void* d_ws, size_t ws_size,
                              hipStream_t stream) {
    const float* x     = (const float*)d_in[0];
    const int*   ei    = (const int*)  d_in[1];
    const float* ew    = (const float*)d_in[2];
    const int*   batch = (const int*)  d_in[3];
    const float* W1    = (const float*)d_in[4];
    const float* b1    = (const float*)d_in[5];
    const float* W2    = (const float*)d_in[6];
    const float* b2    = (const float*)d_in[7];
    const float* Wc    = (const float*)d_in[8];
    const float* bc    = (const float*)d_in[9];
    float* out = (float*)d_out;

    const int* row = ei;
    const int* col = ei + N_EDGES;

    // workspace (R7 footprint, ends at sval+N_PAD): recs | xlA | xlB | csr |
    // rowptr | dis | bsum | boff | sval.
    // H aliases csr (dead before degcsr writes csr). Wt aliases recs.
    // fp8 arrays alias the xlB region (12.8MB): xl8B [0..6.4M) written by gg2,
    // read by gp; xl8A [6.4M..12.8M) written by degcsr tail, read by gg2.
    int2*     recs   = (int2*)d_ws;                              // E int2 = 25.6 MB
    ushort_t* xlA    = (ushort_t*)(recs + N_EDGES);              // N*HID bf16 (gemm1 out)
    ushort_t* xlB    = xlA + (size_t)N_NODES * HID;              // 12.8 MB region
    int2*     csr    = (int2*)(xlB + (size_t)N_NODES * HID);     // E int2
    int*      rowptr = (int*)(csr + N_EDGES);                    // N_PAD
    float*    dis    = (float*)(rowptr + N_PAD);                 // N_PAD
    int*      bsum   = (int*)(dis + N_PAD);                      // 512
    int*      boff   = bsum + 512;                               // 512
    float*    sval   = (float*)(boff + 512);                     // N_PAD
    int*      H      = (int*)csr;                                // NB*NBLK ints = 1.6 MB
    ushort_t* Wt     = (ushort_t*)recs;                          // 2 x [64][128] bf16 = 32 KB
    uchar_t*  xl8B   = (uchar_t*)xlB;                            // 6.4 MB fp8 (layer-2 in)
    uchar_t*  xl8A   = xl8B + (size_t)N_NODES * HID;             // 6.4 MB fp8 (layer-1 in)

    wtprep_kernel   <<<32,   256, 0, stream>>>(W1, Wt);
    bhist_gemm1_kernel<<<NBLK + G1BLK, 256, 0, stream>>>(col, H, x, Wt, xlA);
    scan1_kernel    <<<NB,  1024, 0, stream>>>(H, bsum);
    bscatter_kernel <<<NBLK, 256, 0, stream>>>(row, col, ew, H, bsum, boff, recs);
    degcsr_kernel   <<<NB,  1024, 0, stream>>>(recs, boff, dis, rowptr, csr, xlA, xl8A);
    gather_gemm2_kernel<<<N_NODES / 16, 256, 0, stream>>>(csr, rowptr, dis, xl8A, W2, b1, xl8B);
    gather_pool_kernel <<<N_NODES / 16, 256, 0, stream>>>(csr, rowptr, dis, xl8B, b2, Wc, sval);
    final_out_kernel<<<N_GRAPHS, 256, 0, stream>>>(sval, batch, bc, out);
}

// Round 14
// 307.546 us; speedup vs baseline: 1.1845x; 1.0126x over previous
//
#include <hip/hip_runtime.h>

#define N_NODES 100000
#define N_PAD   100352        // 392*256
#define N_EDGES 3200000
#define IN_DIM  128
#define HID     64
#define N_GRAPHS 256
#define NB      392           // buckets of 256 dest nodes each
#define NBLK    1024          // hist/scatter blocks (25KB lrec -> 4 blocks/CU)
#define EPB     (N_EDGES / NBLK)   // 3125
#define G1ROWS  64                 // rows per gemm1 block (MFMA tile)
#define G1BLK   (N_PAD / G1ROWS)   // 1568 gemm1 blocks
#define BCAP    8960               // degcsr LDS bucket capacity (mean 8192, sigma 90)

typedef unsigned short ushort_t;
typedef unsigned int   uint_t;
typedef unsigned char  uchar_t;
typedef __attribute__((ext_vector_type(4))) float f32x4;
typedef __attribute__((ext_vector_type(2))) float f32x2;
typedef __attribute__((ext_vector_type(8))) short bf16x8;

// bf16 helpers
__device__ __forceinline__ ushort_t f2bf(float v) {          // round-to-nearest-even
    uint_t b = __float_as_uint(v);
    b += 0x7fffu + ((b >> 16) & 1u);
    return (ushort_t)(b >> 16);
}
__device__ __forceinline__ void bf2f2(uint_t u, float& lo, float& hi) {
    lo = __uint_as_float(u << 16);
    hi = __uint_as_float(u & 0xffff0000u);
}
// fp8 e4m3 (OCP) helpers — values stored with x16 scale; consumers fold 1/16 into dis
__device__ __forceinline__ uint_t pk4fp8(float f0, float f1, float f2, float f3) {
    uint_t p = __builtin_amdgcn_cvt_pk_fp8_f32(f0, f1, 0, false);
    p = __builtin_amdgcn_cvt_pk_fp8_f32(f2, f3, p, true);
    return p;
}
__device__ __forceinline__ uchar_t fp8enc(float v) {
    return (uchar_t)(__builtin_amdgcn_cvt_pk_fp8_f32(v, 0.f, 0, false) & 0xFF);
}
// unpack 8 fp8 (uint2) and FMA into accumulators with weight w
__device__ __forceinline__ void fma8f8(float4& a0, float4& a1, const uint2& u, float w) {
    f32x2 p;
    p = __builtin_amdgcn_cvt_pk_f32_fp8(u.x, false); a0.x += p[0] * w; a0.y += p[1] * w;
    p = __builtin_amdgcn_cvt_pk_f32_fp8(u.x, true);  a0.z += p[0] * w; a0.w += p[1] * w;
    p = __builtin_amdgcn_cvt_pk_f32_fp8(u.y, false); a1.x += p[0] * w; a1.y += p[1] * w;
    p = __builtin_amdgcn_cvt_pk_f32_fp8(u.y, true);  a1.z += p[0] * w; a1.w += p[1] * w;
}
// clamped edge-record load: pad slots re-read the last valid record with weight 0
__device__ __forceinline__ int2 ldrec(const int2* __restrict__ csr, int last, int idx) {
    int2 r = csr[idx <= last ? idx : last];
    if (idx > last) r.y = 0;
    return r;
}

// ---------- phase 0: W1 -> transposed split-bf16 planes Wt_hi/Wt_lo [64][128] ----------
__global__ __launch_bounds__(256) void wtprep_kernel(const float* __restrict__ W1,
                                                     ushort_t* __restrict__ Wt) {
    int i = blockIdx.x * 256 + threadIdx.x;      // 0..8191, i = k*64 + c
    int k = i >> 6, c = i & 63;
    float w = W1[i];
    ushort_t hi = f2bf(w);
    float rem = w - __uint_as_float((uint_t)hi << 16);
    ushort_t lo = f2bf(rem);
    Wt[c * 128 + k]        = hi;                 // Wt_hi [64][128]
    Wt[8192 + c * 128 + k] = lo;                 // Wt_lo [64][128]
}

// ---------- phase 1 (fused): bucket histogram (blocks 0..NBLK-1) + MFMA gemm1 ----------
__global__ __launch_bounds__(256) void bhist_gemm1_kernel(
        const int* __restrict__ col, int* __restrict__ H,
        const float* __restrict__ x, const ushort_t* __restrict__ Wt,
        ushort_t* __restrict__ xl) {
    __shared__ char smem[49152];       // hist: 3.1KB | gemm: sA 16K + sBh 16K + sBl 16K
    int tid = threadIdx.x;
    if (blockIdx.x < NBLK) {
        int (*h)[NB] = (int (*)[NB])smem;
        for (int i = tid; i < NB; i += 256) { h[0][i] = 0; h[1][i] = 0; }
        __syncthreads();
        int base = blockIdx.x * EPB;
        int sel = tid & 1;
        for (int j = tid; j < EPB; j += 256) {
            int c = col[base + j];
            atomicAdd(&h[sel][c >> 8], 1);
        }
        __syncthreads();
        for (int i = tid; i < NB; i += 256) H[i * NBLK + blockIdx.x] = h[0][i] + h[1][i];
    } else {
        int bid = blockIdx.x - NBLK;
        ushort_t* sA  = (ushort_t*)smem;          // [64][128] bf16, swizzled
        ushort_t* sBh = sA + 8192;                // [64][128] bf16, swizzled
        ushort_t* sBl = sBh + 8192;
        int r0 = bid * G1ROWS;
        // stage A: thread t -> row t>>2, 32-col chunk (t&3)*32; fp32 -> bf16
        {
            int row = tid >> 2;
            int ck  = (tid & 3) * 32;
            int gr  = r0 + row; if (gr >= N_NODES) gr = 0;     // pad rows: dummy data
            const float4* xs = (const float4*)(x + (size_t)gr * IN_DIM + ck);
            #pragma unroll
            for (int j = 0; j < 4; ++j) {
                float4 a = xs[2 * j], b = xs[2 * j + 1];
                uint4 u;
                u.x = (uint_t)f2bf(a.x) | ((uint_t)f2bf(a.y) << 16);
                u.y = (uint_t)f2bf(a.z) | ((uint_t)f2bf(a.w) << 16);
                u.z = (uint_t)f2bf(b.x) | ((uint_t)f2bf(b.y) << 16);
                u.w = (uint_t)f2bf(b.z) | ((uint_t)f2bf(b.w) << 16);
                int byte = (row * 256 + ck * 2 + j * 16) ^ ((row & 7) << 4);
                *(uint4*)(smem + byte) = u;
            }
            // stage B planes: linear 16B units -> swizzled LDS
            const uint4* wh = (const uint4*)Wt;
            const uint4* wl = (const uint4*)(Wt + 8192);
            #pragma unroll
            for (int j = 0; j < 4; ++j) {
                int u16  = tid * 4 + j;                 // 0..1023
                int colb = u16 >> 4, kc = u16 & 15;
                int byte = (colb * 256 + kc * 16) ^ ((colb & 7) << 4);
                *(uint4*)((char*)sBh + byte) = wh[u16];
                *(uint4*)((char*)sBl + byte) = wl[u16];
            }
        }
        __syncthreads();
        int wv   = tid >> 6, lane = tid & 63;
        int m0   = wv * 16;
        int fr   = lane & 15;
        int fkb  = (lane >> 4) * 16;       // byte offset of k-slice (8 bf16)
        int arow = m0 + fr;
        int aswz = (arow & 7) << 4;
        int bswz = (fr & 7) << 4;
        f32x4 acc0 = {0.f, 0.f, 0.f, 0.f}, acc1 = acc0, acc2 = acc0, acc3 = acc0;
        #pragma unroll
        for (int ks = 0; ks < 4; ++ks) {
            int kb = ks * 64 + fkb;
            bf16x8 af = *(const bf16x8*)((const char*)sA + ((arow * 256 + kb) ^ aswz));
#define BSTEP(ACC, n0) { \
            int bb = (((n0 + fr) * 256 + kb) ^ bswz); \
            bf16x8 bh = *(const bf16x8*)((const char*)sBh + bb); \
            bf16x8 bl = *(const bf16x8*)((const char*)sBl + bb); \
            ACC = __builtin_amdgcn_mfma_f32_16x16x32_bf16(af, bh, ACC, 0, 0, 0); \
            ACC = __builtin_amdgcn_mfma_f32_16x16x32_bf16(af, bl, ACC, 0, 0, 0); }
            BSTEP(acc0, 0) BSTEP(acc1, 16) BSTEP(acc2, 32) BSTEP(acc3, 48)
#undef BSTEP
        }
        // transpose D through LDS (stride 72 bf16), then 2 coalesced uint4 stores
        __syncthreads();                           // all MFMA LDS reads done
        ushort_t* sO = (ushort_t*)smem;            // [64][72] bf16 = 9216 B
        int orow = m0 + (lane >> 4) * 4;
#define TSTORE(reg) { ushort_t* sp = sO + (orow + reg) * 72; \
        sp[fr]      = f2bf(acc0[reg]); sp[fr + 16] = f2bf(acc1[reg]); \
        sp[fr + 32] = f2bf(acc2[reg]); sp[fr + 48] = f2bf(acc3[reg]); }
        TSTORE(0) TSTORE(1) TSTORE(2) TSTORE(3)
#undef TSTORE
        __syncthreads();
        int r  = tid >> 2;                         // 0..63
        int cb = (tid & 3) * 16;                   // col 0/16/32/48
        int gr2 = r0 + r;
        if (gr2 < N_NODES) {
            const uint4* sp = (const uint4*)(sO + r * 72 + cb);
            uint4* dp = (uint4*)(xl + (size_t)gr2 * HID + cb);
            dp[0] = sp[0];
            dp[1] = sp[1];
        }
    }
}

// ---------- phase 2: exclusive scan of H (NB*NBLK, bucket-major), 1024-wide ----------
__global__ __launch_bounds__(1024) void scan1_kernel(int* H, int* __restrict__ bsum) {
    __shared__ int s[NBLK];
    int tid = threadIdx.x;
    int i = blockIdx.x * NBLK + tid;          // blockIdx.x == bucket
    int v = H[i];
    s[tid] = v;
    __syncthreads();
    #pragma unroll
    for (int off = 1; off < NBLK; off <<= 1) {
        int t = (tid >= off) ? s[tid - off] : 0;
        __syncthreads();
        s[tid] += t;
        __syncthreads();
    }
    H[i] = s[tid] - v;                              // exclusive within bucket
    if (tid == NBLK - 1) bsum[blockIdx.x] = s[NBLK - 1];  // bucket total
}

// ---------- phase 3: LDS-staged scatter — bucket-sort in LDS, coalesced burst out ----------
// rec = (row | local<<17, ew); local = col & 255 (8 bits), row < 2^17
__global__ __launch_bounds__(256) void bscatter_kernel(const int* __restrict__ row,
                                                       const int* __restrict__ col,
                                                       const float* __restrict__ ew,
                                                       const int* __restrict__ H,
                                                       const int* __restrict__ bsum,
                                                       int* __restrict__ boff,
                                                       int2* __restrict__ recs) {
    __shared__ int2 lrec[EPB];        // 25 KB: the block's records, bucket-sorted
    __shared__ int  lofs[NB];
    __shared__ int  hcnt[NB];
    __shared__ int  gofs[NB];
    __shared__ int  cur[NB];
    __shared__ int  s[256];
    __shared__ int  carry;
    int tid = threadIdx.x, blk = blockIdx.x;
    if (tid == 0) carry = 0;
    __syncthreads();
    for (int c = 0; c < 2; ++c) {                 // 2*256 >= NB
        int i = c * 256 + tid;
        int v = (i < NB) ? bsum[i] : 0;
        s[tid] = v;
        __syncthreads();
        #pragma unroll
        for (int off = 1; off < 256; off <<= 1) {
            int t = (tid >= off) ? s[tid - off] : 0;
            __syncthreads();
            s[tid] += t;
            __syncthreads();
        }
        if (i < NB) {
            int tb = s[tid] - v + carry;          // bucket start in recs
            int ex = H[i * NBLK + blk];
            gofs[i] = tb + ex;
            hcnt[i] = ((blk < NBLK - 1) ? H[i * NBLK + blk + 1] : v) - ex;
            if (blk == 0) boff[i] = tb;
        }
        __syncthreads();
        if (tid == 0) carry += s[255];
        __syncthreads();
    }
    if (tid == 0) carry = 0;
    __syncthreads();
    for (int c = 0; c < 2; ++c) {
        int i = c * 256 + tid;
        int v = (i < NB) ? hcnt[i] : 0;
        s[tid] = v;
        __syncthreads();
        #pragma unroll
        for (int off = 1; off < 256; off <<= 1) {
            int t = (tid >= off) ? s[tid - off] : 0;
            __syncthreads();
            s[tid] += t;
            __syncthreads();
        }
        if (i < NB) { int l = s[tid] - v + carry; lofs[i] = l; cur[i] = l; }
        __syncthreads();
        if (tid == 0) carry += s[255];
        __syncthreads();
    }
    int base = blk * EPB;
    for (int j = tid; j < EPB; j += 256) {        // scalar coalesced loads (EPB odd)
        int   r = row[base + j];
        int   c = col[base + j];
        float w = ew[base + j];
        int p = atomicAdd(&cur[c >> 8], 1);
        lrec[p] = make_int2(r | ((c & 255) << 17), __float_as_int(w));
    }
    __syncthreads();
    int grp = tid >> 3, gl = tid & 7;             // 32 groups of 8 lanes
    for (int i = grp; i < NB; i += 32) {
        int cnt = hcnt[i], lo = lofs[i], go = gofs[i];
        for (int k = gl; k < cnt; k += 8)
            recs[go + k] = lrec[lo + k];
    }
}

// ---------- phase 3.5 (fused): LDS-staged bucket pass -> deg+cnt -> dis/rowptr ->
// csr permutation scatter -> fp8 scale tail. recs is read ONCE from global
// (coalesced stage into LDS); count + scatter passes run out of LDS.
__global__ __launch_bounds__(1024) void degcsr_kernel(const int2* __restrict__ recs,
                                                      const int* __restrict__ boff,
                                                      float* __restrict__ dis,
                                                      int* __restrict__ rowptr,
                                                      int2* __restrict__ csr,
                                                      const ushort_t* __restrict__ xl,
                                                      uchar_t* __restrict__ xl8) {
    __shared__ int2  lrec[BCAP];        // 70 KB
    __shared__ int   cnt[256];
    __shared__ float degf[256];
    __shared__ int   sscan[256];
    __shared__ int   cur[256];
    int b = blockIdx.x, tid = threadIdx.x;
    if (tid < 256) { cnt[tid] = 0; degf[tid] = 0.f; }
    int s = boff[b], e = (b + 1 < NB) ? boff[b + 1] : N_EDGES;
    int m = e - s;
    int mc = (m < BCAP) ? m : BCAP;
    for (int j = tid; j < mc; j += 1024) lrec[j] = recs[s + j];   // coalesced stage
    __syncthreads();
    // count pass (LDS + rare global tail)
    for (int j = tid; j < mc; j += 1024) {
        int2 r = lrec[j];
        int cl = (r.x >> 17) & 255;
        atomicAdd(&cnt[cl], 1);
        atomicAdd(&degf[cl], __int_as_float(r.y));
    }
    for (int j = mc + tid; j < m; j += 1024) {
        int2 r = recs[s + j];
        int cl = (r.x >> 17) & 255;
        atomicAdd(&cnt[cl], 1);
        atomicAdd(&degf[cl], __int_as_float(r.y));
    }
    __syncthreads();
    int c = (tid < 256) ? cnt[tid] : 0;
    if (tid < 256) sscan[tid] = c;
    __syncthreads();
    #pragma unroll
    for (int off = 1; off < 256; off <<= 1) {
        int t = (tid < 256 && tid >= off) ? sscan[tid - off] : 0;
        __syncthreads();
        if (tid < 256) sscan[tid] += t;
        __syncthreads();
    }
    float d = 0.f;
    if (tid < 256) {
        int rp = s + sscan[tid] - c;              // exclusive; pad nodes get == e
        rowptr[b * 256 + tid] = rp;
        cur[tid] = rp;
        d = 1.0f / sqrtf(fmaxf(1.0f + degf[tid], 1e-30f));
        dis[b * 256 + tid] = d;
    }
    __syncthreads();
    if (tid < 256) degf[tid] = d;                 // reuse as dis cache for the tail
    __syncthreads();
    // csr permutation scatter (records from LDS; rare global tail)
    for (int j = tid; j < mc; j += 1024) {
        int2 r = lrec[j];
        int cl = (r.x >> 17) & 255;
        int pos = atomicAdd(&cur[cl], 1);
        csr[pos] = r;                             // gather masks the local bits
    }
    for (int j = mc + tid; j < m; j += 1024) {
        int2 r = recs[s + j];
        int cl = (r.x >> 17) & 255;
        int pos = atomicAdd(&cur[cl], 1);
        csr[pos] = r;
    }
    // scale tail: xl8 = fp8(16 * dis * xl) for this bucket's 256 rows
    int n0 = b * 256;
    for (int i = tid; i < 256 * 8; i += 1024) {   // 8 bf16-uint4 chunks per row
        int r = i >> 3;
        int n = n0 + r;
        if (n >= N_NODES) break;                  // trailing pad rows
        const uint4* p = (const uint4*)(xl + (size_t)n * HID) + (i & 7);
        float d2 = degf[r] * 16.0f;
        uint4 u = *p;
        float l0, h0, l1, h1, l2, h2, l3, h3;
        bf2f2(u.x, l0, h0); bf2f2(u.y, l1, h1);
        bf2f2(u.z, l2, h2); bf2f2(u.w, l3, h3);
        uint2 o;
        o.x = pk4fp8(l0 * d2, h0 * d2, l1 * d2, h1 * d2);
        o.y = pk4fp8(l2 * d2, h2 * d2, l3 * d2, h3 * d2);
        *((uint2*)(xl8 + (size_t)n * HID) + (i & 7)) = o;   // HID bytes/row
    }
}

// ---------- gather core (fp8): 16 lanes/node (2 groups of 8), contiguous-half split,
// 2-deep pipeline over 4-edge blocks. Row loads are 8B (one cacheline per group). ----------
__device__ __forceinline__ void gather_row16(const int2* __restrict__ csr,
                                             const uchar_t* __restrict__ xl8,
                                             int base, int end, int n,
                                             int g, int c0, int lane,
                                             float4& a0, float4& a1) {
    a0 = make_float4(0.f, 0.f, 0.f, 0.f);
    a1 = make_float4(0.f, 0.f, 0.f, 0.f);
    if (g == 0) {
        uint2 u = *(const uint2*)(xl8 + (uint_t)(n * HID + c0));   // self-loop, w=1
        fma8f8(a0, a1, u, 1.0f);
    }
    int tot  = end - base;
    int half = (tot + 1) >> 1;
    int gs   = base + (g ? half : 0);
    int m    = g ? (tot - half) : half;
    if (m > 0) {
        int last = gs + m - 1;
        int li4  = lane & 3;       // rec slot in block (lanes 4-7 mirror 0-3)
        int gb   = lane & 56;      // group base lane
        int nb   = (m + 3) >> 2;   // number of 4-edge blocks

#define BCI(r_, u0_, u1_, u2_, u3_, w0_, w1_, w2_, w3_) do {                     \
        int r0_ = __shfl((r_).x, gb + 0, 64), r1_ = __shfl((r_).x, gb + 1, 64);  \
        int r2_ = __shfl((r_).x, gb + 2, 64), r3_ = __shfl((r_).x, gb + 3, 64);  \
        w0_ = __int_as_float(__shfl((r_).y, gb + 0, 64));                         \
        w1_ = __int_as_float(__shfl((r_).y, gb + 1, 64));                         \
        w2_ = __int_as_float(__shfl((r_).y, gb + 2, 64));                         \
        w3_ = __int_as_float(__shfl((r_).y, gb + 3, 64));                         \
        u0_ = *(const uint2*)(xl8 + (uint_t)((r0_ & 0x1FFFF) * HID + c0));        \
        u1_ = *(const uint2*)(xl8 + (uint_t)((r1_ & 0x1FFFF) * HID + c0));        \
        u2_ = *(const uint2*)(xl8 + (uint_t)((r2_ & 0x1FFFF) * HID + c0));        \
        u3_ = *(const uint2*)(xl8 + (uint_t)((r3_ & 0x1FFFF) * HID + c0));        \
    } while (0)

        uint2 uA0, uA1, uA2, uA3, uB0, uB1, uB2, uB3;
        float wA0, wA1, wA2, wA3, wB0, wB1, wB2, wB3;
        int2 rA = ldrec(csr, last, gs + li4);
        int2 rB = (nb > 1) ? ldrec(csr, last, gs + 4 + li4) : rA;
        BCI(rA, uA0, uA1, uA2, uA3, wA0, wA1, wA2, wA3);   // block 0 in flight
        int blk = 0;
        while (true) {
            bool hasB  = (blk + 1 < nb);
            bool hasA2 = (blk + 2 < nb);
            if (hasA2) rA = ldrec(csr, last, gs + (blk + 2) * 4 + li4);
            if (hasB) { BCI(rB, uB0, uB1, uB2, uB3, wB0, wB1, wB2, wB3); }
            fma8f8(a0, a1, uA0, wA0); fma8f8(a0, a1, uA1, wA1);
            fma8f8(a0, a1, uA2, wA2); fma8f8(a0, a1, uA3, wA3);
            if (!hasB) break;
            bool hasB2 = (blk + 3 < nb);
            if (hasB2) rB = ldrec(csr, last, gs + (blk + 3) * 4 + li4);
            if (hasA2) { BCI(rA, uA0, uA1, uA2, uA3, wA0, wA1, wA2, wA3); }
            fma8f8(a0, a1, uB0, wB0); fma8f8(a0, a1, uB1, wB1);
            fma8f8(a0, a1, uB2, wB2); fma8f8(a0, a1, uB3, wB3);
            if (!hasA2) break;
            blk += 2;
        }
#undef BCI
    }
    // single-level reduce: combine the two 8-lane groups of this node
    a0.x += __shfl_down(a0.x, 8, 64); a0.y += __shfl_down(a0.y, 8, 64);
    a0.z += __shfl_down(a0.z, 8, 64); a0.w += __shfl_down(a0.w, 8, 64);
    a1.x += __shfl_down(a1.x, 8, 64); a1.y += __shfl_down(a1.y, 8, 64);
    a1.z += __shfl_down(a1.z, 8, 64); a1.w += __shfl_down(a1.w, 8, 64);
}

// ---------- fused gather1 + gemm2: yl2 = dis * (relu(dis*(...) + b1) @ W2) ----------
// 16 nodes per block (4 per wave, 16 lanes each). fp8 in (x16), fp8 out (x16).
__global__ __launch_bounds__(256) void gather_gemm2_kernel(
        const int2* __restrict__ csr, const int* __restrict__ rowptr,
        const float* __restrict__ dis, const uchar_t* __restrict__ xl8,
        const float* __restrict__ W2, const float* __restrict__ b1,
        uchar_t* __restrict__ xl2) {
    __shared__ float sW[HID * HID];     // 16 KB
    __shared__ float sh[16][HID + 4];   // pad 68: breaks row-alias on ds_write_b128
    int tid = threadIdx.x;
    const float4* W4  = (const float4*)W2;
    float4*       sW4 = (float4*)sW;
    #pragma unroll
    for (int i = 0; i < 4; ++i) sW4[tid + 256 * i] = W4[tid + 256 * i];

    int n0   = blockIdx.x * 16;
    int wv   = tid >> 6;
    int lane = tid & 63;
    int lr   = wv * 4 + (lane >> 4);     // local row 0..15
    int n    = n0 + lr;
    int g    = (lane >> 3) & 1;
    int c0   = (lane & 7) << 3;
    int base = rowptr[n], end = rowptr[n + 1];
    float ds = dis[n] * 0.0625f;         // fold the x16 fp8 scale into dis
    float4 a0, a1;
    gather_row16(csr, xl8, base, end, n, g, c0, lane, a0, a1);
    if (g == 0) {
        // h = relu(dis[col]*agg + b1), stored directly (no second pass)
        float4 bb0 = *(const float4*)(b1 + c0);
        float4 bb1 = *(const float4*)(b1 + c0 + 4);
        float4 h0 = make_float4(fmaxf(a0.x * ds + bb0.x, 0.f), fmaxf(a0.y * ds + bb0.y, 0.f),
                                fmaxf(a0.z * ds + bb0.z, 0.f), fmaxf(a0.w * ds + bb0.w, 0.f));
        float4 h1 = make_float4(fmaxf(a1.x * ds + bb1.x, 0.f), fmaxf(a1.y * ds + bb1.y, 0.f),
                                fmaxf(a1.z * ds + bb1.z, 0.f), fmaxf(a1.w * ds + bb1.w, 0.f));
        *(float4*)(&sh[lr][c0])     = h0;
        *(float4*)(&sh[lr][c0 + 4]) = h1;
    }
    __syncthreads();
    // gemm2: each thread computes 4 rows x 1 col; sW value reused 4x per read
    int cc = tid & 63, rq = tid >> 6;
    float acc0 = 0.f, acc1 = 0.f, acc2 = 0.f, acc3 = 0.f;
    #pragma unroll 8
    for (int k = 0; k < HID; ++k) {
        float wk = sW[k * HID + cc];
        acc0 += sh[rq * 4 + 0][k] * wk;
        acc1 += sh[rq * 4 + 1][k] * wk;
        acc2 += sh[rq * 4 + 2][k] * wk;
        acc3 += sh[rq * 4 + 3][k] * wk;
    }
    int o0 = n0 + rq * 4;
    xl2[(size_t)(o0 + 0) * HID + cc] = fp8enc(acc0 * dis[o0 + 0] * 16.0f);
    xl2[(size_t)(o0 + 1) * HID + cc] = fp8enc(acc1 * dis[o0 + 1] * 16.0f);
    xl2[(size_t)(o0 + 2) * HID + cc] = fp8enc(acc2 * dis[o0 + 2] * 16.0f);
    xl2[(size_t)(o0 + 3) * HID + cc] = fp8enc(acc3 * dis[o0 + 3] * 16.0f);
}

// ---------- fused gather2 + pool partial: sval[n] = relu(dis*(...)+b2) . Wc ----------
__global__ __launch_bounds__(256) void gather_pool_kernel(
        const int2* __restrict__ csr, const int* __restrict__ rowptr,
        const float* __restrict__ dis, const uchar_t* __restrict__ xl8,
        const float* __restrict__ b2, const float* __restrict__ Wc,
        float* __restrict__ sval) {
    int tid  = threadIdx.x;
    int n    = (blockIdx.x * 256 + tid) >> 4;           // grid 6250 exact
    int lane = tid & 63;
    int g    = (lane >> 3) & 1;
    int c0   = (lane & 7) << 3;
    int base = rowptr[n], end = rowptr[n + 1];
    float ds = dis[n] * 0.0625f;                        // fold x16 fp8 scale
    float4 a0, a1;
    gather_row16(csr, xl8, base, end, n, g, c0, lane, a0, a1);
    // all lanes compute (g==1 lanes produce garbage that is never read)
    float4 bb0 = *(const float4*)(b2 + c0);
    float4 bb1 = *(const float4*)(b2 + c0 + 4);
    float4 wc0 = *(const float4*)(Wc + c0);
    float4 wc1 = *(const float4*)(Wc + c0 + 4);
    float s = fmaxf(a0.x * ds + bb0.x, 0.f) * wc0.x + fmaxf(a0.y * ds + bb0.y, 0.f) * wc0.y
            + fmaxf(a0.z * ds + bb0.z, 0.f) * wc0.z + fmaxf(a0.w * ds + bb0.w, 0.f) * wc0.w
            + fmaxf(a1.x * ds + bb1.x, 0.f) * wc1.x + fmaxf(a1.y * ds + bb1.y, 0.f) * wc1.y
            + fmaxf(a1.z * ds + bb1.z, 0.f) * wc1.z + fmaxf(a1.w * ds + bb1.w, 0.f) * wc1.w;
    s += __shfl_down(s, 4, 64);
    s += __shfl_down(s, 2, 64);
    s += __shfl_down(s, 1, 64);
    if ((lane & 15) == 0) sval[n] = s;
}

// ---------- final: out[g] = mean(sval over graph range) + bc ----------
__global__ __launch_bounds__(256) void final_out_kernel(const float* __restrict__ sval,
                                                        const int* __restrict__ batch,
                                                        const float* __restrict__ bc,
                                                        float* __restrict__ out) {
    __shared__ float s[256];
    int g = blockIdx.x;   // grid N_GRAPHS
    int lo = 0, hi = N_NODES;
    while (lo < hi) { int m = (lo + hi) >> 1; if (batch[m] < g) lo = m + 1; else hi = m; }
    int start = lo;
    hi = N_NODES;
    while (lo < hi) { int m = (lo + hi) >> 1; if (batch[m] < g + 1) lo = m + 1; else hi = m; }
    int end = lo;
    float acc = 0.f;
    for (int i = start + threadIdx.x; i < end; i += 256) acc += sval[i];
    s[threadIdx.x] = acc;
    __syncthreads();
    #pragma unroll
    for (int off = 128; off > 0; off >>= 1) {
        if (threadIdx.x < off) s[threadIdx.x] += s[threadIdx.x + off];
        __syncthreads();
    }
    if (threadIdx.x == 0)
        out[g] = s[0] / fmaxf((float)(end - start), 1.0f) + bc[0];
}

extern "C" void kernel_launch(void* const* d_in, const int* in_sizes, int n_in,
                              void* d_out, int out_size, void* d_ws, size_t ws_size,
                              hipStream_t stream) {
    const float* x     = (const float*)d_in[0];
    const int*   ei    = (const int*)  d_in[1];
    const float* ew    = (const float*)d_in[2];
    const int*   batch = (const int*)  d_in[3];
    const float* W1    = (const float*)d_in[4];
    const float* b1    = (const float*)d_in[5];
    const float* W2    = (const float*)d_in[6];
    const float* b2    = (const float*)d_in[7];
    const float* Wc    = (const float*)d_in[8];
    const float* bc    = (const float*)d_in[9];
    float* out = (float*)d_out;

    const int* row = ei;
    const int* col = ei + N_EDGES;

    // workspace (R7 footprint, ends at sval+N_PAD): recs | xlA | xlB | csr |
    // rowptr | dis | bsum | boff | sval.
    // H aliases csr (dead before degcsr writes csr). Wt aliases recs.
    // fp8 arrays alias the xlB region (12.8MB): xl8B [0..6.4M) written by gg2,
    // read by gp; xl8A [6.4M..12.8M) written by degcsr tail, read by gg2.
    int2*     recs   = (int2*)d_ws;                              // E int2 = 25.6 MB
    ushort_t* xlA    = (ushort_t*)(recs + N_EDGES);              // N*HID bf16 (gemm1 out)
    ushort_t* xlB    = xlA + (size_t)N_NODES * HID;              // 12.8 MB region
    int2*     csr    = (int2*)(xlB + (size_t)N_NODES * HID);     // E int2
    int*      rowptr = (int*)(csr + N_EDGES);                    // N_PAD
    float*    dis    = (float*)(rowptr + N_PAD);                 // N_PAD
    int*      bsum   = (int*)(dis + N_PAD);                      // 512
    int*      boff   = bsum + 512;                               // 512
    float*    sval   = (float*)(boff + 512);                     // N_PAD
    int*      H      = (int*)csr;                                // NB*NBLK ints = 1.6 MB
    ushort_t* Wt     = (ushort_t*)recs;                          // 2 x [64][128] bf16 = 32 KB
    uchar_t*  xl8B   = (uchar_t*)xlB;                            // 6.4 MB fp8 (layer-2 in)
    uchar_t*  xl8A   = xl8B + (size_t)N_NODES * HID;             // 6.4 MB fp8 (layer-1 in)

    wtprep_kernel   <<<32,   256, 0, stream>>>(W1, Wt);
    bhist_gemm1_kernel<<<NBLK + G1BLK, 256, 0, stream>>>(col, H, x, Wt, xlA);
    scan1_kernel    <<<NB,  1024, 0, stream>>>(H, bsum);
    bscatter_kernel <<<NBLK, 256, 0, stream>>>(row, col, ew, H, bsum, boff, recs);
    degcsr_kernel   <<<NB,  1024, 0, stream>>>(recs, boff, dis, rowptr, csr, xlA, xl8A);
    gather_gemm2_kernel<<<N_NODES / 16, 256, 0, stream>>>(csr, rowptr, dis, xl8A, W2, b1, xl8B);
    gather_pool_kernel <<<N_NODES / 16, 256, 0, stream>>>(csr, rowptr, dis, xl8B, b2, Wc, sval);
    final_out_kernel<<<N_GRAPHS, 256, 0, stream>>>(sval, batch, bc, out);
}